// Round 1
// baseline (1095.464 us; speedup 1.0000x reference)
//
#include <hip/hip_runtime.h>
#include <hip/hip_bf16.h>
#include <math.h>

// Problem constants
constexpr int B  = 16;
constexpr int N  = 8192;     // 2^13
constexpr int E  = 131072;   // 2^17
constexpr int H  = 128;
constexpr int K1 = 4096;
constexpr int K2 = 2048;

// ---------------------------------------------------------------------------
// CSR build (by dst, per graph)
// ---------------------------------------------------------------------------
__global__ __launch_bounds__(256) void count_edges(const int* __restrict__ ei,
                                                   int* __restrict__ cnt) {
  int g = blockIdx.x * 256 + threadIdx.x;      // g < B*E
  int b = g >> 17;
  int e = g & (E - 1);
  int dst = ei[(size_t)b * 2 * E + E + e];
  atomicAdd(&cnt[b * N + dst], 1);
}

__global__ __launch_bounds__(1024) void scan_offsets(int* __restrict__ cnt,
                                                     int* __restrict__ offs) {
  int b = blockIdx.x, t = threadIdx.x;
  __shared__ int sums[1024];
  int base = b * N + t * 8;
  int v[8]; int s = 0;
#pragma unroll
  for (int i = 0; i < 8; ++i) { v[i] = cnt[base + i]; s += v[i]; }
  sums[t] = s; __syncthreads();
  for (int off = 1; off < 1024; off <<= 1) {
    int x = (t >= off) ? sums[t - off] : 0;
    __syncthreads();
    sums[t] += x;
    __syncthreads();
  }
  int run = sums[t] - s;   // exclusive prefix of this thread's chunk
#pragma unroll
  for (int i = 0; i < 8; ++i) {
    offs[b * (N + 1) + t * 8 + i] = run;
    cnt[base + i] = run;                      // becomes fill cursor
    run += v[i];
  }
  if (t == 1023) offs[b * (N + 1) + N] = run; // == E
}

__global__ __launch_bounds__(256) void fill_csr(const int* __restrict__ ei,
                                                int* __restrict__ cur,
                                                int* __restrict__ csr) {
  int g = blockIdx.x * 256 + threadIdx.x;
  int b = g >> 17;
  int e = g & (E - 1);
  int src = ei[(size_t)b * 2 * E + e];
  int dst = ei[(size_t)b * 2 * E + E + e];
  int pos = atomicAdd(&cur[b * N + dst], 1);
  csr[(size_t)b * E + pos] = src;
}

__global__ __launch_bounds__(256) void init_mask(float* __restrict__ mask) {
  int g = blockIdx.x * 256 + threadIdx.x;
  mask[g] = 1.0f;
}

// ---------------------------------------------------------------------------
// GEMM: C[M,128] = A[M,128] @ W[128,128], fp32. Block = 128 rows, 256 threads,
// 8x8 register tile per thread, K chunked by 64, XOR-swizzled A tile in LDS.
// ---------------------------------------------------------------------------
__global__ __launch_bounds__(256, 2) void gemm128(const float* __restrict__ A,
                                                  const float* __restrict__ Wg,
                                                  float* __restrict__ C) {
  __shared__ float As[128 * 64];   // [row][slot], slot = k4 ^ (ty&3), float4 granular
  __shared__ float Wsh[64 * 128];  // [k][col]
  int tid = threadIdx.x;
  int ty = tid >> 4;   // 0..15 : row group (8 rows)
  int tx = tid & 15;   // 0..15 : col group (cols tx*4..+3 and 64+tx*4..+3)
  size_t rowbase = (size_t)blockIdx.x * 128;

  float acc[8][8] = {};

  for (int kc = 0; kc < 2; ++kc) {
    // stage A chunk 128x64 (transpose-free, XOR swizzle on float4 slots)
#pragma unroll
    for (int i = 0; i < 8; ++i) {
      int idx = tid + i * 256;
      int row = idx >> 4, k4 = idx & 15;
      float4 v = *(const float4*)(A + (rowbase + row) * 128 + kc * 64 + k4 * 4);
      int slot = k4 ^ ((row >> 3) & 3);
      *(float4*)(As + row * 64 + slot * 4) = v;
    }
    // stage W chunk 64x128
#pragma unroll
    for (int i = 0; i < 8; ++i) {
      int idx = tid + i * 256;
      int k = idx >> 5, c4 = idx & 31;
      float4 v = *(const float4*)(Wg + (size_t)(kc * 64 + k) * 128 + c4 * 4);
      *(float4*)(Wsh + k * 128 + c4 * 4) = v;
    }
    __syncthreads();

#pragma unroll
    for (int k4 = 0; k4 < 16; ++k4) {
      float4 a4[8];
      int slot = (k4 ^ (ty & 3)) * 4;
#pragma unroll
      for (int i = 0; i < 8; ++i)
        a4[i] = *(const float4*)(As + (ty * 8 + i) * 64 + slot);
#pragma unroll
      for (int kk = 0; kk < 4; ++kk) {
        int k = k4 * 4 + kk;
        float4 wa = *(const float4*)(Wsh + k * 128 + tx * 4);
        float4 wb = *(const float4*)(Wsh + k * 128 + 64 + tx * 4);
#pragma unroll
        for (int i = 0; i < 8; ++i) {
          float a = (kk == 0) ? a4[i].x : (kk == 1) ? a4[i].y : (kk == 2) ? a4[i].z : a4[i].w;
          acc[i][0] += a * wa.x; acc[i][1] += a * wa.y;
          acc[i][2] += a * wa.z; acc[i][3] += a * wa.w;
          acc[i][4] += a * wb.x; acc[i][5] += a * wb.y;
          acc[i][6] += a * wb.z; acc[i][7] += a * wb.w;
        }
      }
    }
    __syncthreads();
  }

#pragma unroll
  for (int i = 0; i < 8; ++i) {
    size_t r = rowbase + ty * 8 + i;
    float4 v1 = {acc[i][0], acc[i][1], acc[i][2], acc[i][3]};
    float4 v2 = {acc[i][4], acc[i][5], acc[i][6], acc[i][7]};
    *(float4*)(C + r * 128 + tx * 4) = v1;
    *(float4*)(C + r * 128 + 64 + tx * 4) = v2;
  }
}

// ---------------------------------------------------------------------------
// degree -> dinv (symmetric norm); dinv==0 <=> node masked out
// ---------------------------------------------------------------------------
__global__ __launch_bounds__(256) void deg_kernel(const float* __restrict__ mask,
                                                  const int* __restrict__ offs,
                                                  const int* __restrict__ csr,
                                                  float* __restrict__ dinv) {
  int g = blockIdx.x * 256 + threadIdx.x;      // < B*N
  int b = g >> 13, n = g & (N - 1);
  float dv = 0.0f;
  if (mask[g] > 0.0f) {
    int o0 = offs[b * (N + 1) + n], o1 = offs[b * (N + 1) + n + 1];
    const int* cs = csr + (size_t)b * E;
    const float* mb = mask + b * N;
    float s = 1.0f;                            // self loop
    for (int j = o0; j < o1; ++j) s += mb[cs[j]];
    dv = rsqrtf(s);
  }
  dinv[g] = dv;
}

// ---------------------------------------------------------------------------
// GCN aggregation: one wave per node. h[n] = relu(dinv*(sum dinv[s]*tmp[s]
// + dinv[n]*tmp[n]) + b) for live nodes, else 0. Optionally fuses the pool's
// per-node dots r = h.wrel, t = h.wroot.
// ---------------------------------------------------------------------------
__global__ __launch_bounds__(256) void gcn_agg(
    const float* __restrict__ tmp, const float* __restrict__ dinv,
    const int* __restrict__ offs, const int* __restrict__ csr,
    const float* __restrict__ bias, float* __restrict__ hout,
    const float* __restrict__ wrel, const float* __restrict__ wroot,
    float* __restrict__ rr, float* __restrict__ tt) {
  int wid = (blockIdx.x * 256 + threadIdx.x) >> 6;   // node id, < B*N
  int lane = threadIdx.x & 63;
  int b = wid >> 13, n = wid & (N - 1);
  float dv = dinv[wid];
  const float* tmpb = tmp + ((size_t)b << 13) * 128;
  const float* dvb  = dinv + (b << 13);
  const int*   cs   = csr + (size_t)b * E;

  float2 acc;
  {
    const float2 s2 = *(const float2*)(tmp + (size_t)wid * 128 + lane * 2);
    acc.x = dv * s2.x; acc.y = dv * s2.y;
  }
  int o0 = offs[b * (N + 1) + n], o1 = offs[b * (N + 1) + n + 1];
  int j = o0;
  for (; j + 1 < o1; j += 2) {
    int s0 = cs[j], s1 = cs[j + 1];
    float w0 = dvb[s0], w1 = dvb[s1];
    if (w0 > 0.0f) {
      const float2 t2 = *(const float2*)(tmpb + (size_t)s0 * 128 + lane * 2);
      acc.x += w0 * t2.x; acc.y += w0 * t2.y;
    }
    if (w1 > 0.0f) {
      const float2 t2 = *(const float2*)(tmpb + (size_t)s1 * 128 + lane * 2);
      acc.x += w1 * t2.x; acc.y += w1 * t2.y;
    }
  }
  if (j < o1) {
    int s0 = cs[j];
    float w0 = dvb[s0];
    if (w0 > 0.0f) {
      const float2 t2 = *(const float2*)(tmpb + (size_t)s0 * 128 + lane * 2);
      acc.x += w0 * t2.x; acc.y += w0 * t2.y;
    }
  }

  float2 outv = {0.0f, 0.0f};
  if (dv > 0.0f) {
    const float2 bb = *(const float2*)(bias + lane * 2);
    outv.x = fmaxf(dv * acc.x + bb.x, 0.0f);
    outv.y = fmaxf(dv * acc.y + bb.y, 0.0f);
  }
  *(float2*)(hout + (size_t)wid * 128 + lane * 2) = outv;

  if (rr != nullptr) {
    const float2 wr = *(const float2*)(wrel + lane * 2);
    const float2 wo = *(const float2*)(wroot + lane * 2);
    float pr = outv.x * wr.x + outv.y * wr.y;
    float pt = outv.x * wo.x + outv.y * wo.y;
#pragma unroll
    for (int d = 32; d > 0; d >>= 1) {
      pr += __shfl_down(pr, d);
      pt += __shfl_down(pt, d);
    }
    if (lane == 0) { rr[wid] = pr; tt[wid] = pt; }
  }
}

// ---------------------------------------------------------------------------
// pool score: score[n] = mask[n]*(sum_in r[src] + t[n] + b)
// ---------------------------------------------------------------------------
__global__ __launch_bounds__(256) void score_agg(const float* __restrict__ r,
                                                 const float* __restrict__ t,
                                                 const float* __restrict__ pb,
                                                 const float* __restrict__ mask,
                                                 const int* __restrict__ offs,
                                                 const int* __restrict__ csr,
                                                 float* __restrict__ score) {
  int g = blockIdx.x * 256 + threadIdx.x;
  int b = g >> 13, n = g & (N - 1);
  float scv = 0.0f;
  if (mask[g] > 0.0f) {
    int o0 = offs[b * (N + 1) + n], o1 = offs[b * (N + 1) + n + 1];
    const int* cs = csr + (size_t)b * E;
    const float* rb = r + b * N;
    float s = pb[0] + t[g];
    for (int j = o0; j < o1; ++j) s += rb[cs[j]];   // r==0 for dead srcs
    scv = s;
  }
  score[g] = scv;
}

// ---------------------------------------------------------------------------
// top-k via radix select on order-preserving uint keys; index-ordered ties.
// One block per graph; writes the new mask (1.0/0.0).
// ---------------------------------------------------------------------------
__device__ __forceinline__ unsigned fkey(float s, float m) {
  if (m <= 0.0f) return 0u;
  unsigned u = __float_as_uint(s);
  return (u & 0x80000000u) ? ~u : (u | 0x80000000u);
}

__global__ __launch_bounds__(1024) void topk_kernel(const float* __restrict__ score,
                                                    float* __restrict__ mask, int k) {
  int b = blockIdx.x, tid = threadIdx.x;
  const float* sc = score + b * N;
  float* mk = mask + b * N;
  __shared__ int hist[256];
  __shared__ int sbuf[1024];
  __shared__ unsigned sh_prefix;
  __shared__ int sh_kneed;

  unsigned prefix = 0, hm = 0;
  int kneed = k;
  for (int shift = 24; shift >= 0; shift -= 8) {
    if (tid < 256) hist[tid] = 0;
    __syncthreads();
    for (int i = tid; i < N; i += 1024) {
      unsigned key = fkey(sc[i], mk[i]);
      if ((key & hm) == prefix) atomicAdd(&hist[(key >> shift) & 255], 1);
    }
    __syncthreads();
    if (tid == 0) {
      int c = 0, bsel = 0;
      for (int bb = 255; bb >= 0; --bb) {
        int hc = hist[bb];
        if (c + hc >= kneed) { bsel = bb; break; }
        c += hc;
      }
      sh_prefix = prefix | ((unsigned)bsel << shift);
      sh_kneed = kneed - c;
    }
    __syncthreads();
    prefix = sh_prefix;
    kneed = sh_kneed;
    hm |= (0xFFu << shift);
    __syncthreads();
  }

  unsigned T = prefix;              // key of the k-th largest
  int base = tid * 8;
  unsigned keys[8];
  int eqf[8];
  int cnt = 0;
#pragma unroll
  for (int q = 0; q < 8; ++q) {
    keys[q] = fkey(sc[base + q], mk[base + q]);
    eqf[q] = (keys[q] == T) ? 1 : 0;
    cnt += eqf[q];
  }
  sbuf[tid] = cnt; __syncthreads();
  for (int off = 1; off < 1024; off <<= 1) {
    int x = (tid >= off) ? sbuf[tid - off] : 0;
    __syncthreads();
    sbuf[tid] += x;
    __syncthreads();
  }
  int ex = sbuf[tid] - cnt;         // rank base among ties (index order)
#pragma unroll
  for (int q = 0; q < 8; ++q) {
    bool sel = (keys[q] > T) || (eqf[q] && (ex < kneed));
    ex += eqf[q];
    mk[base + q] = sel ? 1.0f : 0.0f;
  }
}

// ---------------------------------------------------------------------------
// pool apply: h *= tanh(score) * new_mask
// ---------------------------------------------------------------------------
__global__ __launch_bounds__(256) void pool_apply(float* __restrict__ h,
                                                  const float* __restrict__ score,
                                                  const float* __restrict__ mask) {
  int g = blockIdx.x * 256 + threadIdx.x;  // < B*N*32
  int i = g >> 5, q = g & 31;
  float f = tanhf(score[i]) * mask[i];
  float4* ptr = (float4*)(h + (size_t)i * 128 + q * 4);
  float4 v = *ptr;
  v.x *= f; v.y *= f; v.z *= f; v.w *= f;
  *ptr = v;
}

// ---------------------------------------------------------------------------
// readout partials + head MLP + log_softmax
// ---------------------------------------------------------------------------
__global__ __launch_bounds__(256) void readout(const float* __restrict__ h,
                                               float* __restrict__ part) {
  int b = blockIdx.x, c = blockIdx.y;
  int tid = threadIdx.x;
  int f = tid & 127, half = tid >> 7;
  float acc = 0.0f;
  for (int n = c * 256 + half; n < (c + 1) * 256; n += 2)
    acc += h[((size_t)b * N + n) * 128 + f];
  __shared__ float red[256];
  red[tid] = acc; __syncthreads();
  if (half == 0) part[((size_t)b * 32 + c) * 128 + f] = red[f] + red[f + 128];
}

__global__ __launch_bounds__(128) void head(const float* __restrict__ part,
                                            const float* __restrict__ l1w,
                                            const float* __restrict__ l1b,
                                            const float* __restrict__ l2w,
                                            const float* __restrict__ l2b,
                                            float* __restrict__ out) {
  int b = blockIdx.x, f = threadIdx.x;
  float g = 0.0f;
  for (int c = 0; c < 32; ++c) g += part[((size_t)b * 32 + c) * 128 + f];
  g *= (1.0f / (float)K2);
  __shared__ float gs[128], hh[128], lg[10];
  gs[f] = g; __syncthreads();
  float a = l1b[f];
  for (int kk = 0; kk < 128; ++kk) a += gs[kk] * l1w[kk * 128 + f];
  hh[f] = fmaxf(a, 0.0f); __syncthreads();
  if (f < 10) {
    float l = l2b[f];
    for (int j = 0; j < 128; ++j) l += hh[j] * l2w[j * 10 + f];
    lg[f] = l;
  }
  __syncthreads();
  if (f == 0) {
    float m = lg[0];
    for (int c = 1; c < 10; ++c) m = fmaxf(m, lg[c]);
    float s = 0.0f;
    for (int c = 0; c < 10; ++c) s += expf(lg[c] - m);
    float lse = m + logf(s);
    for (int c = 0; c < 10; ++c) out[b * 10 + c] = lg[c] - lse;
  }
}

// ---------------------------------------------------------------------------
extern "C" void kernel_launch(void* const* d_in, const int* in_sizes, int n_in,
                              void* d_out, int out_size, void* d_ws, size_t ws_size,
                              hipStream_t stream) {
  (void)in_sizes; (void)n_in; (void)out_size; (void)ws_size;
  const float* x       = (const float*)d_in[0];
  const int*   ei      = (const int*)d_in[1];
  const float* W1      = (const float*)d_in[2];
  const float* b1      = (const float*)d_in[3];
  const float* p1_wrel = (const float*)d_in[4];
  const float* p1_wroot= (const float*)d_in[5];
  const float* p1_b    = (const float*)d_in[6];
  const float* W2      = (const float*)d_in[7];
  const float* b2      = (const float*)d_in[8];
  const float* p2_wrel = (const float*)d_in[9];
  const float* p2_wroot= (const float*)d_in[10];
  const float* p2_b    = (const float*)d_in[11];
  const float* W3      = (const float*)d_in[12];
  const float* b3      = (const float*)d_in[13];
  const float* l1w     = (const float*)d_in[14];
  const float* l1b     = (const float*)d_in[15];
  const float* l2w     = (const float*)d_in[16];
  const float* l2b     = (const float*)d_in[17];
  float* out = (float*)d_out;

  // workspace carve-up (~140 MB total)
  char* p = (char*)d_ws;
  auto alloc = [&](size_t bytes) {
    char* r = p;
    p += ((bytes + 255) & ~(size_t)255);
    return r;
  };
  float* h     = (float*)alloc((size_t)B * N * H * 4);
  float* tmp   = (float*)alloc((size_t)B * N * H * 4);
  int*   offs  = (int*)alloc((size_t)B * (N + 1) * 4);
  int*   cur   = (int*)alloc((size_t)B * N * 4);
  int*   csr   = (int*)alloc((size_t)B * E * 4);
  float* dinv  = (float*)alloc((size_t)B * N * 4);
  float* mask  = (float*)alloc((size_t)B * N * 4);
  float* rr    = (float*)alloc((size_t)B * N * 4);
  float* tt    = (float*)alloc((size_t)B * N * 4);
  float* score = (float*)alloc((size_t)B * N * 4);
  float* part  = (float*)alloc((size_t)B * 32 * H * 4);

  // CSR build
  hipMemsetAsync(cur, 0, (size_t)B * N * 4, stream);
  count_edges<<<B * E / 256, 256, 0, stream>>>(ei, cur);
  scan_offsets<<<B, 1024, 0, stream>>>(cur, offs);
  fill_csr<<<B * E / 256, 256, 0, stream>>>(ei, cur, csr);
  init_mask<<<B * N / 256, 256, 0, stream>>>(mask);

  // ---- layer 1 + pool 1
  gemm128<<<(B * N) / 128, 256, 0, stream>>>(x, W1, tmp);
  deg_kernel<<<B * N / 256, 256, 0, stream>>>(mask, offs, csr, dinv);
  gcn_agg<<<B * N / 4, 256, 0, stream>>>(tmp, dinv, offs, csr, b1, h,
                                         p1_wrel, p1_wroot, rr, tt);
  score_agg<<<B * N / 256, 256, 0, stream>>>(rr, tt, p1_b, mask, offs, csr, score);
  topk_kernel<<<B, 1024, 0, stream>>>(score, mask, K1);
  pool_apply<<<B * N * 32 / 256, 256, 0, stream>>>(h, score, mask);

  // ---- layer 2 + pool 2
  gemm128<<<(B * N) / 128, 256, 0, stream>>>(h, W2, tmp);
  deg_kernel<<<B * N / 256, 256, 0, stream>>>(mask, offs, csr, dinv);
  gcn_agg<<<B * N / 4, 256, 0, stream>>>(tmp, dinv, offs, csr, b2, h,
                                         p2_wrel, p2_wroot, rr, tt);
  score_agg<<<B * N / 256, 256, 0, stream>>>(rr, tt, p2_b, mask, offs, csr, score);
  topk_kernel<<<B, 1024, 0, stream>>>(score, mask, K2);
  pool_apply<<<B * N * 32 / 256, 256, 0, stream>>>(h, score, mask);

  // ---- layer 3
  gemm128<<<(B * N) / 128, 256, 0, stream>>>(h, W3, tmp);
  deg_kernel<<<B * N / 256, 256, 0, stream>>>(mask, offs, csr, dinv);
  gcn_agg<<<B * N / 4, 256, 0, stream>>>(tmp, dinv, offs, csr, b3, h,
                                         nullptr, nullptr, nullptr, nullptr);

  // ---- readout + head
  readout<<<dim3(B, 32), 256, 0, stream>>>(h, part);
  head<<<B, 128, 0, stream>>>(part, l1w, l1b, l2w, l2b, out);
}

// Round 2
// 854.647 us; speedup vs baseline: 1.2818x; 1.2818x over previous
//
#include <hip/hip_runtime.h>
#include <hip/hip_bf16.h>
#include <math.h>

// Problem constants
constexpr int B  = 16;
constexpr int N  = 8192;     // 2^13
constexpr int E  = 131072;   // 2^17
constexpr int H  = 128;
constexpr int K1 = 4096;
constexpr int K2 = 2048;

// ---------------------------------------------------------------------------
// CSR build (by dst, per graph)
// ---------------------------------------------------------------------------
__global__ __launch_bounds__(256) void count_edges(const int* __restrict__ ei,
                                                   int* __restrict__ cnt) {
  int g = blockIdx.x * 256 + threadIdx.x;      // g < B*E
  int b = g >> 17;
  int e = g & (E - 1);
  int dst = ei[(size_t)b * 2 * E + E + e];
  atomicAdd(&cnt[b * N + dst], 1);
}

__global__ __launch_bounds__(1024) void scan_offsets(int* __restrict__ cnt,
                                                     int* __restrict__ offs) {
  int b = blockIdx.x, t = threadIdx.x;
  __shared__ int sums[1024];
  int base = b * N + t * 8;
  int v[8]; int s = 0;
#pragma unroll
  for (int i = 0; i < 8; ++i) { v[i] = cnt[base + i]; s += v[i]; }
  sums[t] = s; __syncthreads();
  for (int off = 1; off < 1024; off <<= 1) {
    int x = (t >= off) ? sums[t - off] : 0;
    __syncthreads();
    sums[t] += x;
    __syncthreads();
  }
  int run = sums[t] - s;   // exclusive prefix of this thread's chunk
#pragma unroll
  for (int i = 0; i < 8; ++i) {
    offs[b * (N + 1) + t * 8 + i] = run;
    cnt[base + i] = run;                      // becomes fill cursor
    run += v[i];
  }
  if (t == 1023) offs[b * (N + 1) + N] = run; // == E
}

__global__ __launch_bounds__(256) void fill_csr(const int* __restrict__ ei,
                                                int* __restrict__ cur,
                                                int* __restrict__ csr) {
  int g = blockIdx.x * 256 + threadIdx.x;
  int b = g >> 17;
  int e = g & (E - 1);
  int src = ei[(size_t)b * 2 * E + e];
  int dst = ei[(size_t)b * 2 * E + E + e];
  int pos = atomicAdd(&cur[b * N + dst], 1);
  csr[(size_t)b * E + pos] = src;
}

// ---------------------------------------------------------------------------
// GEMM: C[M,128] = (A[M,128] * fscale[M]) @ W[128,128], fp32.
// Block = 128 rows, 256 threads, 8x8 register tile, K chunked by 64,
// XOR-swizzled A tile in LDS. fscale==nullptr -> no row scaling.
// ---------------------------------------------------------------------------
__global__ __launch_bounds__(256, 2) void gemm128(const float* __restrict__ A,
                                                  const float* __restrict__ Wg,
                                                  float* __restrict__ C,
                                                  const float* __restrict__ fscale) {
  __shared__ float As[128 * 64];   // [row][slot], slot = k4 ^ ((row>>3)&3)
  __shared__ float Wsh[64 * 128];  // [k][col]
  int tid = threadIdx.x;
  int ty = tid >> 4;   // 0..15 : row group (8 rows)
  int tx = tid & 15;   // 0..15 : col group
  size_t rowbase = (size_t)blockIdx.x * 128;

  float acc[8][8] = {};

  for (int kc = 0; kc < 2; ++kc) {
#pragma unroll
    for (int i = 0; i < 8; ++i) {
      int idx = tid + i * 256;
      int row = idx >> 4, k4 = idx & 15;
      float4 v = *(const float4*)(A + (rowbase + row) * 128 + kc * 64 + k4 * 4);
      if (fscale != nullptr) {
        float f = fscale[rowbase + row];
        v.x *= f; v.y *= f; v.z *= f; v.w *= f;
      }
      int slot = k4 ^ ((row >> 3) & 3);
      *(float4*)(As + row * 64 + slot * 4) = v;
    }
#pragma unroll
    for (int i = 0; i < 8; ++i) {
      int idx = tid + i * 256;
      int k = idx >> 5, c4 = idx & 31;
      float4 v = *(const float4*)(Wg + (size_t)(kc * 64 + k) * 128 + c4 * 4);
      *(float4*)(Wsh + k * 128 + c4 * 4) = v;
    }
    __syncthreads();

#pragma unroll
    for (int k4 = 0; k4 < 16; ++k4) {
      float4 a4[8];
      int slot = (k4 ^ (ty & 3)) * 4;
#pragma unroll
      for (int i = 0; i < 8; ++i)
        a4[i] = *(const float4*)(As + (ty * 8 + i) * 64 + slot);
#pragma unroll
      for (int kk = 0; kk < 4; ++kk) {
        int k = k4 * 4 + kk;
        float4 wa = *(const float4*)(Wsh + k * 128 + tx * 4);
        float4 wb = *(const float4*)(Wsh + k * 128 + 64 + tx * 4);
#pragma unroll
        for (int i = 0; i < 8; ++i) {
          float a = (kk == 0) ? a4[i].x : (kk == 1) ? a4[i].y : (kk == 2) ? a4[i].z : a4[i].w;
          acc[i][0] += a * wa.x; acc[i][1] += a * wa.y;
          acc[i][2] += a * wa.z; acc[i][3] += a * wa.w;
          acc[i][4] += a * wb.x; acc[i][5] += a * wb.y;
          acc[i][6] += a * wb.z; acc[i][7] += a * wb.w;
        }
      }
    }
    __syncthreads();
  }

#pragma unroll
  for (int i = 0; i < 8; ++i) {
    size_t r = rowbase + ty * 8 + i;
    float4 v1 = {acc[i][0], acc[i][1], acc[i][2], acc[i][3]};
    float4 v2 = {acc[i][4], acc[i][5], acc[i][6], acc[i][7]};
    *(float4*)(C + r * 128 + tx * 4) = v1;
    *(float4*)(C + r * 128 + 64 + tx * 4) = v2;
  }
}

// ---------------------------------------------------------------------------
// layer-1 dinv: all nodes live, deg = in-degree + 1 (self loop)
// ---------------------------------------------------------------------------
__global__ __launch_bounds__(256) void deg_init(const int* __restrict__ offs,
                                                float* __restrict__ dinv) {
  int g = blockIdx.x * 256 + threadIdx.x;      // < B*N
  int b = g >> 13, n = g & (N - 1);
  int d = offs[b * (N + 1) + n + 1] - offs[b * (N + 1) + n];
  dinv[g] = rsqrtf((float)d + 1.0f);
}

// ---------------------------------------------------------------------------
// dinv with mask: 16 lanes per node, lane-parallel mask gather.
// ---------------------------------------------------------------------------
__global__ __launch_bounds__(256) void deg_masked(const float* __restrict__ mask,
                                                  const int* __restrict__ offs,
                                                  const int* __restrict__ csr,
                                                  float* __restrict__ dinv) {
  int grp = threadIdx.x >> 4;                  // 16 nodes per block
  int gl  = threadIdx.x & 15;
  int nid = blockIdx.x * 16 + grp;             // < B*N
  int b = nid >> 13, n = nid & (N - 1);
  float m = mask[nid];
  float s = 0.0f;
  if (m > 0.0f) {
    int o0 = offs[b * (N + 1) + n], o1 = offs[b * (N + 1) + n + 1];
    const int* cs = csr + (size_t)b * E;
    const float* mb = mask + b * N;
    for (int base = o0; base < o1; base += 16)
      if (base + gl < o1) s += mb[cs[base + gl]];
  }
#pragma unroll
  for (int d = 8; d > 0; d >>= 1) s += __shfl_xor(s, d, 16);
  if (gl == 0) dinv[nid] = (m > 0.0f) ? rsqrtf(s + 1.0f) : 0.0f;
}

// ---------------------------------------------------------------------------
// GCN aggregation v2: one wave per node, lane-parallel edge metadata,
// 8-deep batched row gathers, XCD-swizzled block->graph mapping.
// h[n] = relu(dv*(sum_src dv_s*tmp[s] + dv*tmp[n]) + b); fused pool dots.
// ---------------------------------------------------------------------------
__global__ __launch_bounds__(256) void gcn_agg2(
    const float* __restrict__ tmp, const float* __restrict__ dinv,
    const int* __restrict__ offs, const int* __restrict__ csr,
    const float* __restrict__ bias, float* __restrict__ hout,
    const float* __restrict__ wrel, const float* __restrict__ wroot,
    float* __restrict__ rr, float* __restrict__ tt) {
  // 32768 blocks; blockIdx&7 selects XCD (round-robin dispatch), each XCD
  // owns 2 graphs so its gathers touch only 8 MB of tmp.
  int blk = blockIdx.x;
  int xcd = blk & 7;
  int j   = blk >> 3;                      // 0..4095
  int b   = xcd * 2 + (j >> 11);           // 2048 blocks per graph
  int n   = (j & 2047) * 4 + (threadIdx.x >> 6);
  int wid = b * N + n;
  int lane = threadIdx.x & 63;

  float dv = dinv[wid];
  float* hrow = hout + (size_t)wid * 128;

  if (dv <= 0.0f) {                         // dead destination: zeros only
    *(float2*)(hrow + lane * 2) = make_float2(0.0f, 0.0f);
    if (rr != nullptr && lane == 0) { rr[wid] = 0.0f; tt[wid] = 0.0f; }
    return;
  }

  const float* tmpb = tmp + ((size_t)b << 13) * 128;
  const float* dvb  = dinv + (b << 13);
  const int*   cs   = csr + (size_t)b * E;

  float2 acc;
  {
    const float2 s2 = *(const float2*)(tmpb + (size_t)n * 128 + lane * 2);
    acc.x = dv * s2.x; acc.y = dv * s2.y;   // self loop (dinv^2 after outer dv)
  }

  int o0 = offs[b * (N + 1) + n], o1 = offs[b * (N + 1) + n + 1];
  for (int base = o0; base < o1; base += 64) {
    int nv = o1 - base; if (nv > 64) nv = 64;
    // lane-parallel metadata: 64 edge indices + their dinv in 2 loads
    int   sl = (lane < nv) ? cs[base + lane] : 0;
    float wl = (lane < nv) ? dvb[sl] : 0.0f;   // 0 also for dead sources

    for (int i0 = 0; i0 < nv; i0 += 8) {
      float2 r8[8]; float w8[8];
#pragma unroll
      for (int q = 0; q < 8; ++q) {
        int idx = i0 + q;                     // always < 64 (see nv bound)
        int   sq = __shfl(sl, idx);
        float wq = __shfl(wl, idx);           // 0 for pad / dead src
        w8[q] = wq;
        if (wq > 0.0f)                        // wave-uniform branch
          r8[q] = *(const float2*)(tmpb + (size_t)sq * 128 + lane * 2);
        else
          r8[q] = make_float2(0.0f, 0.0f);
      }
#pragma unroll
      for (int q = 0; q < 8; ++q) {
        acc.x += w8[q] * r8[q].x;
        acc.y += w8[q] * r8[q].y;
      }
    }
  }

  const float2 bb = *(const float2*)(bias + lane * 2);
  float2 outv;
  outv.x = fmaxf(dv * acc.x + bb.x, 0.0f);
  outv.y = fmaxf(dv * acc.y + bb.y, 0.0f);
  *(float2*)(hrow + lane * 2) = outv;

  if (rr != nullptr) {                        // fused pool dots r=h.wrel t=h.wroot
    const float2 wr = *(const float2*)(wrel + lane * 2);
    const float2 wo = *(const float2*)(wroot + lane * 2);
    float pr = outv.x * wr.x + outv.y * wr.y;
    float pt = outv.x * wo.x + outv.y * wo.y;
#pragma unroll
    for (int d = 32; d > 0; d >>= 1) {
      pr += __shfl_down(pr, d);
      pt += __shfl_down(pt, d);
    }
    if (lane == 0) { rr[wid] = pr; tt[wid] = pt; }
  }
}

// ---------------------------------------------------------------------------
// pool score: score[n] = mask[n]*(sum_in r[src] + t[n] + b); 16 lanes/node.
// mask==nullptr means all nodes live (layer 1).
// ---------------------------------------------------------------------------
__global__ __launch_bounds__(256) void score_agg(const float* __restrict__ r,
                                                 const float* __restrict__ t,
                                                 const float* __restrict__ pb,
                                                 const float* __restrict__ mask,
                                                 const int* __restrict__ offs,
                                                 const int* __restrict__ csr,
                                                 float* __restrict__ score) {
  int grp = threadIdx.x >> 4;
  int gl  = threadIdx.x & 15;
  int nid = blockIdx.x * 16 + grp;
  int b = nid >> 13, n = nid & (N - 1);
  bool live = (mask == nullptr) || (mask[nid] > 0.0f);
  float s = 0.0f;
  if (live) {
    int o0 = offs[b * (N + 1) + n], o1 = offs[b * (N + 1) + n + 1];
    const int* cs = csr + (size_t)b * E;
    const float* rb = r + b * N;
    for (int base = o0; base < o1; base += 16)
      if (base + gl < o1) s += rb[cs[base + gl]];   // r==0 for dead srcs
  }
#pragma unroll
  for (int d = 8; d > 0; d >>= 1) s += __shfl_xor(s, d, 16);
  if (gl == 0) score[nid] = live ? (s + t[nid] + pb[0]) : 0.0f;
}

// ---------------------------------------------------------------------------
// top-k via radix select; index-ordered ties. Writes new mask AND the fused
// pool scale fscale = tanh(score)*new_mask (consumed by the next GEMM).
// ---------------------------------------------------------------------------
__device__ __forceinline__ unsigned fkey(float s, float m) {
  if (m <= 0.0f) return 0u;
  unsigned u = __float_as_uint(s);
  return (u & 0x80000000u) ? ~u : (u | 0x80000000u);
}

__global__ __launch_bounds__(1024) void topk_kernel(const float* __restrict__ score,
                                                    const float* __restrict__ mkin,
                                                    float* __restrict__ mkout,
                                                    float* __restrict__ fscale,
                                                    int k) {
  int b = blockIdx.x, tid = threadIdx.x;
  const float* sc = score + b * N;
  float* mk = mkout + b * N;
  float* fs = fscale + b * N;
  __shared__ int hist[256];
  __shared__ int sbuf[1024];
  __shared__ unsigned sh_prefix;
  __shared__ int sh_kneed;

  unsigned prefix = 0, hm = 0;
  int kneed = k;
  for (int shift = 24; shift >= 0; shift -= 8) {
    if (tid < 256) hist[tid] = 0;
    __syncthreads();
    for (int i = tid; i < N; i += 1024) {
      float m = (mkin == nullptr) ? 1.0f : mkin[b * N + i];
      unsigned key = fkey(sc[i], m);
      if ((key & hm) == prefix) atomicAdd(&hist[(key >> shift) & 255], 1);
    }
    __syncthreads();
    if (tid == 0) {
      int c = 0, bsel = 0;
      for (int bb2 = 255; bb2 >= 0; --bb2) {
        int hc = hist[bb2];
        if (c + hc >= kneed) { bsel = bb2; break; }
        c += hc;
      }
      sh_prefix = prefix | ((unsigned)bsel << shift);
      sh_kneed = kneed - c;
    }
    __syncthreads();
    prefix = sh_prefix;
    kneed = sh_kneed;
    hm |= (0xFFu << shift);
    __syncthreads();
  }

  unsigned T = prefix;              // key of the k-th largest
  int base = tid * 8;
  unsigned keys[8];
  int eqf[8];
  int cnt = 0;
#pragma unroll
  for (int q = 0; q < 8; ++q) {
    float m = (mkin == nullptr) ? 1.0f : mkin[b * N + base + q];
    keys[q] = fkey(sc[base + q], m);
    eqf[q] = (keys[q] == T) ? 1 : 0;
    cnt += eqf[q];
  }
  sbuf[tid] = cnt; __syncthreads();
  for (int off = 1; off < 1024; off <<= 1) {
    int x = (tid >= off) ? sbuf[tid - off] : 0;
    __syncthreads();
    sbuf[tid] += x;
    __syncthreads();
  }
  int ex = sbuf[tid] - cnt;         // rank base among ties (index order)
#pragma unroll
  for (int q = 0; q < 8; ++q) {
    bool sel = (keys[q] > T) || (eqf[q] && (ex < kneed));
    ex += eqf[q];
    mk[base + q] = sel ? 1.0f : 0.0f;
    fs[base + q] = sel ? tanhf(sc[base + q]) : 0.0f;
  }
}

// ---------------------------------------------------------------------------
// readout partials + head MLP + log_softmax
// ---------------------------------------------------------------------------
__global__ __launch_bounds__(256) void readout(const float* __restrict__ h,
                                               float* __restrict__ part) {
  int b = blockIdx.x, c = blockIdx.y;
  int tid = threadIdx.x;
  int f = tid & 127, half = tid >> 7;
  float acc = 0.0f;
  for (int n = c * 256 + half; n < (c + 1) * 256; n += 2)
    acc += h[((size_t)b * N + n) * 128 + f];
  __shared__ float red[256];
  red[tid] = acc; __syncthreads();
  if (half == 0) part[((size_t)b * 32 + c) * 128 + f] = red[f] + red[f + 128];
}

__global__ __launch_bounds__(128) void head(const float* __restrict__ part,
                                            const float* __restrict__ l1w,
                                            const float* __restrict__ l1b,
                                            const float* __restrict__ l2w,
                                            const float* __restrict__ l2b,
                                            float* __restrict__ out) {
  int b = blockIdx.x, f = threadIdx.x;
  float g = 0.0f;
  for (int c = 0; c < 32; ++c) g += part[((size_t)b * 32 + c) * 128 + f];
  g *= (1.0f / (float)K2);
  __shared__ float gs[128], hh[128], lg[10];
  gs[f] = g; __syncthreads();
  float a = l1b[f];
  for (int kk = 0; kk < 128; ++kk) a += gs[kk] * l1w[kk * 128 + f];
  hh[f] = fmaxf(a, 0.0f); __syncthreads();
  if (f < 10) {
    float l = l2b[f];
    for (int j = 0; j < 128; ++j) l += hh[j] * l2w[j * 10 + f];
    lg[f] = l;
  }
  __syncthreads();
  if (f == 0) {
    float m = lg[0];
    for (int c = 1; c < 10; ++c) m = fmaxf(m, lg[c]);
    float s = 0.0f;
    for (int c = 0; c < 10; ++c) s += expf(lg[c] - m);
    float lse = m + logf(s);
    for (int c = 0; c < 10; ++c) out[b * 10 + c] = lg[c] - lse;
  }
}

// ---------------------------------------------------------------------------
extern "C" void kernel_launch(void* const* d_in, const int* in_sizes, int n_in,
                              void* d_out, int out_size, void* d_ws, size_t ws_size,
                              hipStream_t stream) {
  (void)in_sizes; (void)n_in; (void)out_size; (void)ws_size;
  const float* x       = (const float*)d_in[0];
  const int*   ei      = (const int*)d_in[1];
  const float* W1      = (const float*)d_in[2];
  const float* b1      = (const float*)d_in[3];
  const float* p1_wrel = (const float*)d_in[4];
  const float* p1_wroot= (const float*)d_in[5];
  const float* p1_b    = (const float*)d_in[6];
  const float* W2      = (const float*)d_in[7];
  const float* b2      = (const float*)d_in[8];
  const float* p2_wrel = (const float*)d_in[9];
  const float* p2_wroot= (const float*)d_in[10];
  const float* p2_b    = (const float*)d_in[11];
  const float* W3      = (const float*)d_in[12];
  const float* b3      = (const float*)d_in[13];
  const float* l1w     = (const float*)d_in[14];
  const float* l1b     = (const float*)d_in[15];
  const float* l2w     = (const float*)d_in[16];
  const float* l2b     = (const float*)d_in[17];
  float* out = (float*)d_out;

  // workspace carve-up
  char* p = (char*)d_ws;
  auto alloc = [&](size_t bytes) {
    char* r = p;
    p += ((bytes + 255) & ~(size_t)255);
    return r;
  };
  float* h      = (float*)alloc((size_t)B * N * H * 4);
  float* tmp    = (float*)alloc((size_t)B * N * H * 4);
  int*   offs   = (int*)alloc((size_t)B * (N + 1) * 4);
  int*   cur    = (int*)alloc((size_t)B * N * 4);
  int*   csr    = (int*)alloc((size_t)B * E * 4);
  float* dinv   = (float*)alloc((size_t)B * N * 4);
  float* mask   = (float*)alloc((size_t)B * N * 4);
  float* rr     = (float*)alloc((size_t)B * N * 4);
  float* tt     = (float*)alloc((size_t)B * N * 4);
  float* score  = (float*)alloc((size_t)B * N * 4);
  float* fscale = (float*)alloc((size_t)B * N * 4);
  float* part   = (float*)alloc((size_t)B * 32 * H * 4);

  // CSR build
  hipMemsetAsync(cur, 0, (size_t)B * N * 4, stream);
  count_edges<<<B * E / 256, 256, 0, stream>>>(ei, cur);
  scan_offsets<<<B, 1024, 0, stream>>>(cur, offs);
  fill_csr<<<B * E / 256, 256, 0, stream>>>(ei, cur, csr);

  // ---- layer 1 + pool 1 (all nodes live: fast dinv, no mask)
  gemm128<<<(B * N) / 128, 256, 0, stream>>>(x, W1, tmp, nullptr);
  deg_init<<<B * N / 256, 256, 0, stream>>>(offs, dinv);
  gcn_agg2<<<B * N / 4, 256, 0, stream>>>(tmp, dinv, offs, csr, b1, h,
                                          p1_wrel, p1_wroot, rr, tt);
  score_agg<<<B * N / 16, 256, 0, stream>>>(rr, tt, p1_b, nullptr, offs, csr, score);
  topk_kernel<<<B, 1024, 0, stream>>>(score, nullptr, mask, fscale, K1);

  // ---- layer 2 + pool 2 (pool-1 scaling fused into GEMM A-stage)
  gemm128<<<(B * N) / 128, 256, 0, stream>>>(h, W2, tmp, fscale);
  deg_masked<<<B * N / 16, 256, 0, stream>>>(mask, offs, csr, dinv);
  gcn_agg2<<<B * N / 4, 256, 0, stream>>>(tmp, dinv, offs, csr, b2, h,
                                          p2_wrel, p2_wroot, rr, tt);
  score_agg<<<B * N / 16, 256, 0, stream>>>(rr, tt, p2_b, mask, offs, csr, score);
  topk_kernel<<<B, 1024, 0, stream>>>(score, mask, mask, fscale, K2);

  // ---- layer 3
  gemm128<<<(B * N) / 128, 256, 0, stream>>>(h, W3, tmp, fscale);
  deg_masked<<<B * N / 16, 256, 0, stream>>>(mask, offs, csr, dinv);
  gcn_agg2<<<B * N / 4, 256, 0, stream>>>(tmp, dinv, offs, csr, b3, h,
                                          nullptr, nullptr, nullptr, nullptr);

  // ---- readout + head
  readout<<<dim3(B, 32), 256, 0, stream>>>(h, part);
  head<<<B, 128, 0, stream>>>(part, l1w, l1b, l2w, l2b, out);
}

// Round 3
// 687.916 us; speedup vs baseline: 1.5924x; 1.2424x over previous
//
#include <hip/hip_runtime.h>
#include <hip/hip_bf16.h>
#include <math.h>

// Problem constants
constexpr int B  = 16;
constexpr int N  = 8192;     // 2^13
constexpr int E  = 131072;   // 2^17
constexpr int H  = 128;
constexpr int K1 = 4096;
constexpr int K2 = 2048;

typedef __attribute__((ext_vector_type(8))) short short8;
typedef __attribute__((ext_vector_type(4))) float floatx4;

__device__ __forceinline__ unsigned short f2bf(float f) {
  unsigned u = __float_as_uint(f);
  return (unsigned short)((u + 0x7FFFu + ((u >> 16) & 1u)) >> 16);  // RNE
}
__device__ __forceinline__ float bf2f(unsigned short s) {
  return __uint_as_float(((unsigned)s) << 16);
}

// ---------------------------------------------------------------------------
// CSR build (by dst, per graph)
// ---------------------------------------------------------------------------
__global__ __launch_bounds__(256) void count_edges(const int* __restrict__ ei,
                                                   int* __restrict__ cnt) {
  int g = blockIdx.x * 256 + threadIdx.x;      // g < B*E
  int b = g >> 17;
  int e = g & (E - 1);
  int dst = ei[(size_t)b * 2 * E + E + e];
  atomicAdd(&cnt[b * N + dst], 1);
}

__global__ __launch_bounds__(1024) void scan_offsets(int* __restrict__ cnt,
                                                     int* __restrict__ offs) {
  int b = blockIdx.x, t = threadIdx.x;
  __shared__ int sums[1024];
  int base = b * N + t * 8;
  int v[8]; int s = 0;
#pragma unroll
  for (int i = 0; i < 8; ++i) { v[i] = cnt[base + i]; s += v[i]; }
  sums[t] = s; __syncthreads();
  for (int off = 1; off < 1024; off <<= 1) {
    int x = (t >= off) ? sums[t - off] : 0;
    __syncthreads();
    sums[t] += x;
    __syncthreads();
  }
  int run = sums[t] - s;   // exclusive prefix of this thread's chunk
#pragma unroll
  for (int i = 0; i < 8; ++i) {
    offs[b * (N + 1) + t * 8 + i] = run;
    cnt[base + i] = run;                      // becomes fill cursor
    run += v[i];
  }
  if (t == 1023) offs[b * (N + 1) + N] = run; // == E
}

__global__ __launch_bounds__(256) void fill_csr(const int* __restrict__ ei,
                                                int* __restrict__ cur,
                                                int* __restrict__ csr) {
  int g = blockIdx.x * 256 + threadIdx.x;
  int b = g >> 17;
  int e = g & (E - 1);
  int src = ei[(size_t)b * 2 * E + e];
  int dst = ei[(size_t)b * 2 * E + E + e];
  int pos = atomicAdd(&cur[b * N + dst], 1);
  csr[(size_t)b * E + pos] = src;
}

// ---------------------------------------------------------------------------
// W[128][128] fp32 -> Wt[128][128] bf16 transposed (N-major), for MFMA B-frags
// ---------------------------------------------------------------------------
__global__ __launch_bounds__(256) void prep_wt(const float* __restrict__ W,
                                               unsigned short* __restrict__ Wt) {
  for (int i = threadIdx.x; i < 128 * 128; i += 256) {
    int k = i >> 7, n = i & 127;
    Wt[n * 128 + k] = f2bf(W[i]);
  }
}

// ---------------------------------------------------------------------------
// MFMA GEMM: C[M,128](bf16) = (A[M,128]*fscale) @ W, W given as Wt[n][k] bf16.
// 256 thr = 4 waves; wave owns 32 rows (2 groups of 16); no LDS, no barriers.
// v_mfma_f32_16x16x32_bf16: A lane l: row=l&15, k=8*(l>>4)+j.
//                           B lane l: col=l&15, k=8*(l>>4)+j  (from Wt rows).
//                           D lane l: col=l&15, row=(l>>4)*4+reg.
// ---------------------------------------------------------------------------
template <bool ABF16>
__global__ __launch_bounds__(256) void gemm_mfma(const void* __restrict__ Ap,
                                                 const unsigned short* __restrict__ Wt,
                                                 unsigned short* __restrict__ Cb,
                                                 const float* __restrict__ fscale) {
  int wv   = threadIdx.x >> 6;
  int lane = threadIdx.x & 63;
  int l15  = lane & 15, lg = lane >> 4;
  size_t rowbase = (size_t)blockIdx.x * 128 + wv * 32;

  short8 afrag[2][4];
#pragma unroll
  for (int rg = 0; rg < 2; ++rg) {
    size_t row = rowbase + rg * 16 + l15;
    float fs = (fscale != nullptr) ? fscale[row] : 1.0f;
#pragma unroll
    for (int c = 0; c < 4; ++c) {
      int k0 = c * 32 + lg * 8;
      short8 a;
      if (ABF16) {
        const unsigned short* p = (const unsigned short*)Ap + row * 128 + k0;
        uint4 u = *(const uint4*)p;
        unsigned w[4] = {u.x, u.y, u.z, u.w};
#pragma unroll
        for (int q = 0; q < 4; ++q) {
          a[2 * q]     = (short)f2bf(bf2f((unsigned short)(w[q] & 0xFFFFu)) * fs);
          a[2 * q + 1] = (short)f2bf(bf2f((unsigned short)(w[q] >> 16)) * fs);
        }
      } else {
        const float* p = (const float*)Ap + row * 128 + k0;
        float4 v0 = *(const float4*)p;
        float4 v1 = *(const float4*)(p + 4);
        a[0] = (short)f2bf(v0.x * fs); a[1] = (short)f2bf(v0.y * fs);
        a[2] = (short)f2bf(v0.z * fs); a[3] = (short)f2bf(v0.w * fs);
        a[4] = (short)f2bf(v1.x * fs); a[5] = (short)f2bf(v1.y * fs);
        a[6] = (short)f2bf(v1.z * fs); a[7] = (short)f2bf(v1.w * fs);
      }
      afrag[rg][c] = a;
    }
  }

#pragma unroll
  for (int t = 0; t < 8; ++t) {
    int col = t * 16 + l15;
    short8 bfrag[4];
#pragma unroll
    for (int c = 0; c < 4; ++c)
      bfrag[c] = *(const short8*)(Wt + col * 128 + c * 32 + lg * 8);

    floatx4 acc0 = {0.f, 0.f, 0.f, 0.f};
    floatx4 acc1 = {0.f, 0.f, 0.f, 0.f};
#pragma unroll
    for (int c = 0; c < 4; ++c) {
      acc0 = __builtin_amdgcn_mfma_f32_16x16x32_bf16(afrag[0][c], bfrag[c], acc0, 0, 0, 0);
      acc1 = __builtin_amdgcn_mfma_f32_16x16x32_bf16(afrag[1][c], bfrag[c], acc1, 0, 0, 0);
    }
#pragma unroll
    for (int r = 0; r < 4; ++r) {
      size_t row0 = rowbase + lg * 4 + r;
      size_t row1 = rowbase + 16 + lg * 4 + r;
      Cb[row0 * 128 + t * 16 + l15] = f2bf(acc0[r]);
      Cb[row1 * 128 + t * 16 + l15] = f2bf(acc1[r]);
    }
  }
}

// ---------------------------------------------------------------------------
// layer-1 dinv: all nodes live, deg = in-degree + 1 (self loop)
// ---------------------------------------------------------------------------
__global__ __launch_bounds__(256) void deg_init(const int* __restrict__ offs,
                                                float* __restrict__ dinv) {
  int g = blockIdx.x * 256 + threadIdx.x;      // < B*N
  int b = g >> 13, n = g & (N - 1);
  int d = offs[b * (N + 1) + n + 1] - offs[b * (N + 1) + n];
  dinv[g] = rsqrtf((float)d + 1.0f);
}

// ---------------------------------------------------------------------------
// dinv with mask: 16 lanes per node, lane-parallel mask gather.
// ---------------------------------------------------------------------------
__global__ __launch_bounds__(256) void deg_masked(const float* __restrict__ mask,
                                                  const int* __restrict__ offs,
                                                  const int* __restrict__ csr,
                                                  float* __restrict__ dinv) {
  int grp = threadIdx.x >> 4;                  // 16 nodes per block
  int gl  = threadIdx.x & 15;
  int nid = blockIdx.x * 16 + grp;             // < B*N
  int b = nid >> 13, n = nid & (N - 1);
  float m = mask[nid];
  float s = 0.0f;
  if (m > 0.0f) {
    int o0 = offs[b * (N + 1) + n], o1 = offs[b * (N + 1) + n + 1];
    const int* cs = csr + (size_t)b * E;
    const float* mb = mask + b * N;
    for (int base = o0; base < o1; base += 16)
      if (base + gl < o1) s += mb[cs[base + gl]];
  }
#pragma unroll
  for (int d = 8; d > 0; d >>= 1) s += __shfl_xor(s, d, 16);
  if (gl == 0) dinv[nid] = (m > 0.0f) ? rsqrtf(s + 1.0f) : 0.0f;
}

// ---------------------------------------------------------------------------
// GCN aggregation: one wave per node, bf16 feature rows (4 B/lane = 2 cols),
// lane-parallel edge metadata, 8-deep batched gathers, XCD-swizzled blocks.
// ---------------------------------------------------------------------------
__global__ __launch_bounds__(256) void gcn_agg2(
    const unsigned short* __restrict__ tmp, const float* __restrict__ dinv,
    const int* __restrict__ offs, const int* __restrict__ csr,
    const float* __restrict__ bias, unsigned short* __restrict__ hout,
    const float* __restrict__ wrel, const float* __restrict__ wroot,
    float* __restrict__ rr, float* __restrict__ tt) {
  int blk = blockIdx.x;
  int xcd = blk & 7;
  int j   = blk >> 3;                      // 0..4095
  int b   = xcd * 2 + (j >> 11);           // 2 graphs per XCD
  int n   = (j & 2047) * 4 + (threadIdx.x >> 6);
  int wid = b * N + n;
  int lane = threadIdx.x & 63;

  float dv = dinv[wid];
  unsigned* hrow = (unsigned*)hout + (size_t)wid * 64;

  if (dv <= 0.0f) {                         // dead destination: zeros only
    hrow[lane] = 0u;
    if (rr != nullptr && lane == 0) { rr[wid] = 0.0f; tt[wid] = 0.0f; }
    return;
  }

  const unsigned* tmpb = (const unsigned*)tmp + ((size_t)b << 13) * 64;
  const float* dvb = dinv + (b << 13);
  const int*   cs  = csr + (size_t)b * E;

  float2 acc;
  {
    unsigned u = tmpb[(size_t)n * 64 + lane];
    acc.x = dv * bf2f((unsigned short)(u & 0xFFFFu));
    acc.y = dv * bf2f((unsigned short)(u >> 16));
  }

  int o0 = offs[b * (N + 1) + n], o1 = offs[b * (N + 1) + n + 1];
  for (int base = o0; base < o1; base += 64) {
    int nv = o1 - base; if (nv > 64) nv = 64;
    int   sl = (lane < nv) ? cs[base + lane] : 0;
    float wl = (lane < nv) ? dvb[sl] : 0.0f;   // 0 also for dead sources

    for (int i0 = 0; i0 < nv; i0 += 8) {
      unsigned r8[8]; float w8[8];
#pragma unroll
      for (int q = 0; q < 8; ++q) {
        int idx = i0 + q;
        int   sq = __shfl(sl, idx);
        float wq = __shfl(wl, idx);
        w8[q] = wq;
        r8[q] = (wq > 0.0f) ? tmpb[(size_t)sq * 64 + lane] : 0u;  // wave-uniform
      }
#pragma unroll
      for (int q = 0; q < 8; ++q) {
        acc.x += w8[q] * bf2f((unsigned short)(r8[q] & 0xFFFFu));
        acc.y += w8[q] * bf2f((unsigned short)(r8[q] >> 16));
      }
    }
  }

  const float2 bb = *(const float2*)(bias + lane * 2);
  float2 outv;
  outv.x = fmaxf(dv * acc.x + bb.x, 0.0f);
  outv.y = fmaxf(dv * acc.y + bb.y, 0.0f);
  hrow[lane] = ((unsigned)f2bf(outv.y) << 16) | (unsigned)f2bf(outv.x);

  if (rr != nullptr) {                        // fused pool dots (fp32 inputs)
    const float2 wr = *(const float2*)(wrel + lane * 2);
    const float2 wo = *(const float2*)(wroot + lane * 2);
    float pr = outv.x * wr.x + outv.y * wr.y;
    float pt = outv.x * wo.x + outv.y * wo.y;
#pragma unroll
    for (int d = 32; d > 0; d >>= 1) {
      pr += __shfl_down(pr, d);
      pt += __shfl_down(pt, d);
    }
    if (lane == 0) { rr[wid] = pr; tt[wid] = pt; }
  }
}

// ---------------------------------------------------------------------------
// pool score: score[n] = mask[n]*(sum_in r[src] + t[n] + b); 16 lanes/node.
// ---------------------------------------------------------------------------
__global__ __launch_bounds__(256) void score_agg(const float* __restrict__ r,
                                                 const float* __restrict__ t,
                                                 const float* __restrict__ pb,
                                                 const float* __restrict__ mask,
                                                 const int* __restrict__ offs,
                                                 const int* __restrict__ csr,
                                                 float* __restrict__ score) {
  int grp = threadIdx.x >> 4;
  int gl  = threadIdx.x & 15;
  int nid = blockIdx.x * 16 + grp;
  int b = nid >> 13, n = nid & (N - 1);
  bool live = (mask == nullptr) || (mask[nid] > 0.0f);
  float s = 0.0f;
  if (live) {
    int o0 = offs[b * (N + 1) + n], o1 = offs[b * (N + 1) + n + 1];
    const int* cs = csr + (size_t)b * E;
    const float* rb = r + b * N;
    for (int base = o0; base < o1; base += 16)
      if (base + gl < o1) s += rb[cs[base + gl]];   // r==0 for dead srcs
  }
#pragma unroll
  for (int d = 8; d > 0; d >>= 1) s += __shfl_xor(s, d, 16);
  if (gl == 0) score[nid] = live ? (s + t[nid] + pb[0]) : 0.0f;
}

// ---------------------------------------------------------------------------
// top-k via radix select; index-ordered ties. Writes new mask AND the fused
// pool scale fscale = tanh(score)*new_mask (consumed by the next GEMM).
// ---------------------------------------------------------------------------
__device__ __forceinline__ unsigned fkey(float s, float m) {
  if (m <= 0.0f) return 0u;
  unsigned u = __float_as_uint(s);
  return (u & 0x80000000u) ? ~u : (u | 0x80000000u);
}

__global__ __launch_bounds__(1024) void topk_kernel(const float* __restrict__ score,
                                                    const float* __restrict__ mkin,
                                                    float* __restrict__ mkout,
                                                    float* __restrict__ fscale,
                                                    int k) {
  int b = blockIdx.x, tid = threadIdx.x;
  const float* sc = score + b * N;
  float* mk = mkout + b * N;
  float* fs = fscale + b * N;
  __shared__ int hist[256];
  __shared__ int sbuf[1024];
  __shared__ unsigned sh_prefix;
  __shared__ int sh_kneed;

  unsigned prefix = 0, hm = 0;
  int kneed = k;
  for (int shift = 24; shift >= 0; shift -= 8) {
    if (tid < 256) hist[tid] = 0;
    __syncthreads();
    for (int i = tid; i < N; i += 1024) {
      float m = (mkin == nullptr) ? 1.0f : mkin[b * N + i];
      unsigned key = fkey(sc[i], m);
      if ((key & hm) == prefix) atomicAdd(&hist[(key >> shift) & 255], 1);
    }
    __syncthreads();
    if (tid == 0) {
      int c = 0, bsel = 0;
      for (int bb2 = 255; bb2 >= 0; --bb2) {
        int hc = hist[bb2];
        if (c + hc >= kneed) { bsel = bb2; break; }
        c += hc;
      }
      sh_prefix = prefix | ((unsigned)bsel << shift);
      sh_kneed = kneed - c;
    }
    __syncthreads();
    prefix = sh_prefix;
    kneed = sh_kneed;
    hm |= (0xFFu << shift);
    __syncthreads();
  }

  unsigned T = prefix;              // key of the k-th largest
  int base = tid * 8;
  unsigned keys[8];
  int eqf[8];
  int cnt = 0;
#pragma unroll
  for (int q = 0; q < 8; ++q) {
    float m = (mkin == nullptr) ? 1.0f : mkin[b * N + base + q];
    keys[q] = fkey(sc[base + q], m);
    eqf[q] = (keys[q] == T) ? 1 : 0;
    cnt += eqf[q];
  }
  sbuf[tid] = cnt; __syncthreads();
  for (int off = 1; off < 1024; off <<= 1) {
    int x = (tid >= off) ? sbuf[tid - off] : 0;
    __syncthreads();
    sbuf[tid] += x;
    __syncthreads();
  }
  int ex = sbuf[tid] - cnt;         // rank base among ties (index order)
#pragma unroll
  for (int q = 0; q < 8; ++q) {
    bool sel = (keys[q] > T) || (eqf[q] && (ex < kneed));
    ex += eqf[q];
    mk[base + q] = sel ? 1.0f : 0.0f;
    fs[base + q] = sel ? tanhf(sc[base + q]) : 0.0f;
  }
}

// ---------------------------------------------------------------------------
// readout partials (bf16 h) + head MLP + log_softmax
// ---------------------------------------------------------------------------
__global__ __launch_bounds__(256) void readout(const unsigned short* __restrict__ h,
                                               float* __restrict__ part) {
  int b = blockIdx.x, c = blockIdx.y;
  int tid = threadIdx.x;
  int f = tid & 127, half = tid >> 7;
  float acc = 0.0f;
  for (int n = c * 256 + half; n < (c + 1) * 256; n += 2)
    acc += bf2f(h[((size_t)b * N + n) * 128 + f]);
  __shared__ float red[256];
  red[tid] = acc; __syncthreads();
  if (half == 0) part[((size_t)b * 32 + c) * 128 + f] = red[f] + red[f + 128];
}

__global__ __launch_bounds__(128) void head(const float* __restrict__ part,
                                            const float* __restrict__ l1w,
                                            const float* __restrict__ l1b,
                                            const float* __restrict__ l2w,
                                            const float* __restrict__ l2b,
                                            float* __restrict__ out) {
  int b = blockIdx.x, f = threadIdx.x;
  float g = 0.0f;
  for (int c = 0; c < 32; ++c) g += part[((size_t)b * 32 + c) * 128 + f];
  g *= (1.0f / (float)K2);
  __shared__ float gs[128], hh[128], lg[10];
  gs[f] = g; __syncthreads();
  float a = l1b[f];
  for (int kk = 0; kk < 128; ++kk) a += gs[kk] * l1w[kk * 128 + f];
  hh[f] = fmaxf(a, 0.0f); __syncthreads();
  if (f < 10) {
    float l = l2b[f];
    for (int j = 0; j < 128; ++j) l += hh[j] * l2w[j * 10 + f];
    lg[f] = l;
  }
  __syncthreads();
  if (f == 0) {
    float m = lg[0];
    for (int c = 1; c < 10; ++c) m = fmaxf(m, lg[c]);
    float s = 0.0f;
    for (int c = 0; c < 10; ++c) s += expf(lg[c] - m);
    float lse = m + logf(s);
    for (int c = 0; c < 10; ++c) out[b * 10 + c] = lg[c] - lse;
  }
}

// ---------------------------------------------------------------------------
extern "C" void kernel_launch(void* const* d_in, const int* in_sizes, int n_in,
                              void* d_out, int out_size, void* d_ws, size_t ws_size,
                              hipStream_t stream) {
  (void)in_sizes; (void)n_in; (void)out_size; (void)ws_size;
  const float* x       = (const float*)d_in[0];
  const int*   ei      = (const int*)d_in[1];
  const float* W1      = (const float*)d_in[2];
  const float* b1      = (const float*)d_in[3];
  const float* p1_wrel = (const float*)d_in[4];
  const float* p1_wroot= (const float*)d_in[5];
  const float* p1_b    = (const float*)d_in[6];
  const float* W2      = (const float*)d_in[7];
  const float* b2      = (const float*)d_in[8];
  const float* p2_wrel = (const float*)d_in[9];
  const float* p2_wroot= (const float*)d_in[10];
  const float* p2_b    = (const float*)d_in[11];
  const float* W3      = (const float*)d_in[12];
  const float* b3      = (const float*)d_in[13];
  const float* l1w     = (const float*)d_in[14];
  const float* l1b     = (const float*)d_in[15];
  const float* l2w     = (const float*)d_in[16];
  const float* l2b     = (const float*)d_in[17];
  float* out = (float*)d_out;

  // workspace carve-up
  char* p = (char*)d_ws;
  auto alloc = [&](size_t bytes) {
    char* r = p;
    p += ((bytes + 255) & ~(size_t)255);
    return r;
  };
  unsigned short* h   = (unsigned short*)alloc((size_t)B * N * H * 2);   // bf16
  unsigned short* tmp = (unsigned short*)alloc((size_t)B * N * H * 2);   // bf16
  int*   offs   = (int*)alloc((size_t)B * (N + 1) * 4);
  int*   cur    = (int*)alloc((size_t)B * N * 4);
  int*   csr    = (int*)alloc((size_t)B * E * 4);
  float* dinv   = (float*)alloc((size_t)B * N * 4);
  float* mask   = (float*)alloc((size_t)B * N * 4);
  float* rr     = (float*)alloc((size_t)B * N * 4);
  float* tt     = (float*)alloc((size_t)B * N * 4);
  float* score  = (float*)alloc((size_t)B * N * 4);
  float* fscale = (float*)alloc((size_t)B * N * 4);
  float* part   = (float*)alloc((size_t)B * 32 * H * 4);
  unsigned short* Wt1 = (unsigned short*)alloc(128 * 128 * 2);
  unsigned short* Wt2 = (unsigned short*)alloc(128 * 128 * 2);
  unsigned short* Wt3 = (unsigned short*)alloc(128 * 128 * 2);

  // CSR build + weight prep
  hipMemsetAsync(cur, 0, (size_t)B * N * 4, stream);
  count_edges<<<B * E / 256, 256, 0, stream>>>(ei, cur);
  scan_offsets<<<B, 1024, 0, stream>>>(cur, offs);
  fill_csr<<<B * E / 256, 256, 0, stream>>>(ei, cur, csr);
  prep_wt<<<1, 256, 0, stream>>>(W1, Wt1);
  prep_wt<<<1, 256, 0, stream>>>(W2, Wt2);
  prep_wt<<<1, 256, 0, stream>>>(W3, Wt3);

  // ---- layer 1 + pool 1 (all nodes live)
  gemm_mfma<false><<<(B * N) / 128, 256, 0, stream>>>(x, Wt1, tmp, nullptr);
  deg_init<<<B * N / 256, 256, 0, stream>>>(offs, dinv);
  gcn_agg2<<<B * N / 4, 256, 0, stream>>>(tmp, dinv, offs, csr, b1, h,
                                          p1_wrel, p1_wroot, rr, tt);
  score_agg<<<B * N / 16, 256, 0, stream>>>(rr, tt, p1_b, nullptr, offs, csr, score);
  topk_kernel<<<B, 1024, 0, stream>>>(score, nullptr, mask, fscale, K1);

  // ---- layer 2 + pool 2 (pool-1 scaling fused into GEMM A-frag load)
  gemm_mfma<true><<<(B * N) / 128, 256, 0, stream>>>(h, Wt2, tmp, fscale);
  deg_masked<<<B * N / 16, 256, 0, stream>>>(mask, offs, csr, dinv);
  gcn_agg2<<<B * N / 4, 256, 0, stream>>>(tmp, dinv, offs, csr, b2, h,
                                          p2_wrel, p2_wroot, rr, tt);
  score_agg<<<B * N / 16, 256, 0, stream>>>(rr, tt, p2_b, mask, offs, csr, score);
  topk_kernel<<<B, 1024, 0, stream>>>(score, mask, mask, fscale, K2);

  // ---- layer 3
  gemm_mfma<true><<<(B * N) / 128, 256, 0, stream>>>(h, Wt3, tmp, fscale);
  deg_masked<<<B * N / 16, 256, 0, stream>>>(mask, offs, csr, dinv);
  gcn_agg2<<<B * N / 4, 256, 0, stream>>>(tmp, dinv, offs, csr, b3, h,
                                          nullptr, nullptr, nullptr, nullptr);

  // ---- readout + head
  readout<<<dim3(B, 32), 256, 0, stream>>>(h, part);
  head<<<B, 128, 0, stream>>>(part, l1w, l1b, l2w, l2b, out);
}

// Round 4
// 596.039 us; speedup vs baseline: 1.8379x; 1.1541x over previous
//
#include <hip/hip_runtime.h>
#include <hip/hip_bf16.h>
#include <math.h>

// Problem constants
constexpr int B  = 16;
constexpr int N  = 8192;     // 2^13
constexpr int E  = 131072;   // 2^17
constexpr int H  = 128;
constexpr int K1 = 4096;
constexpr int K2 = 2048;

typedef __attribute__((ext_vector_type(8))) short short8;
typedef __attribute__((ext_vector_type(4))) float floatx4;

__device__ __forceinline__ unsigned short f2bf(float f) {
  unsigned u = __float_as_uint(f);
  return (unsigned short)((u + 0x7FFFu + ((u >> 16) & 1u)) >> 16);  // RNE
}
__device__ __forceinline__ float bf2f(unsigned short s) {
  return __uint_as_float(((unsigned)s) << 16);
}
__device__ __forceinline__ int rdlane_i(int v, int l) {
  return __builtin_amdgcn_readlane(v, l);
}
__device__ __forceinline__ float rdlane_f(float v, int l) {
  return __uint_as_float((unsigned)__builtin_amdgcn_readlane((int)__float_as_uint(v), l));
}

// ---------------------------------------------------------------------------
// CSR build (by dst, per graph) — XCD-local: blockIdx&7 = XCD, 2 graphs/XCD,
// so each graph's cnt/csr lines live in exactly one L2 (kills the 13x write
// amplification seen in R3: WRITE_SIZE 106 MB for an 8 MB csr).
// ---------------------------------------------------------------------------
__global__ __launch_bounds__(256) void count_edges(const int* __restrict__ ei,
                                                   int* __restrict__ cnt) {
  int blk = blockIdx.x;                        // 8192 blocks
  int j = blk >> 3;                            // 0..1023
  int b = (blk & 7) * 2 + (j >> 9);            // graph
  int e = ((j & 511) << 8) + threadIdx.x;      // edge within graph
  int dst = ei[(size_t)b * 2 * E + E + e];
  atomicAdd(&cnt[b * N + dst], 1);
}

__global__ __launch_bounds__(1024) void scan_offsets(int* __restrict__ cnt,
                                                     int* __restrict__ offs) {
  int b = blockIdx.x, t = threadIdx.x;
  __shared__ int sums[1024];
  int base = b * N + t * 8;
  int v[8]; int s = 0;
#pragma unroll
  for (int i = 0; i < 8; ++i) { v[i] = cnt[base + i]; s += v[i]; }
  sums[t] = s; __syncthreads();
  for (int off = 1; off < 1024; off <<= 1) {
    int x = (t >= off) ? sums[t - off] : 0;
    __syncthreads();
    sums[t] += x;
    __syncthreads();
  }
  int run = sums[t] - s;   // exclusive prefix of this thread's chunk
#pragma unroll
  for (int i = 0; i < 8; ++i) {
    offs[b * (N + 1) + t * 8 + i] = run;
    cnt[base + i] = run;                      // becomes fill cursor
    run += v[i];
  }
  if (t == 1023) offs[b * (N + 1) + N] = run; // == E
}

__global__ __launch_bounds__(256) void fill_csr(const int* __restrict__ ei,
                                                int* __restrict__ cur,
                                                int* __restrict__ csr) {
  int blk = blockIdx.x;
  int j = blk >> 3;
  int b = (blk & 7) * 2 + (j >> 9);
  int e = ((j & 511) << 8) + threadIdx.x;
  int src = ei[(size_t)b * 2 * E + e];
  int dst = ei[(size_t)b * 2 * E + E + e];
  int pos = atomicAdd(&cur[b * N + dst], 1);
  csr[(size_t)b * E + pos] = src;
}

// ---------------------------------------------------------------------------
// W[128][128] fp32 -> Wt[128][128] bf16 transposed (N-major), for MFMA B-frags
// ---------------------------------------------------------------------------
__global__ __launch_bounds__(256) void prep_wt(const float* __restrict__ W,
                                               unsigned short* __restrict__ Wt) {
  for (int i = threadIdx.x; i < 128 * 128; i += 256) {
    int k = i >> 7, n = i & 127;
    Wt[n * 128 + k] = f2bf(W[i]);
  }
}

// ---------------------------------------------------------------------------
// MFMA GEMM: C[M,128](bf16) = (A[M,128]*fscale) @ W, W given as Wt[n][k] bf16.
// 256 thr = 4 waves; wave owns 32 rows; no LDS, no barriers.
// ---------------------------------------------------------------------------
template <bool ABF16>
__global__ __launch_bounds__(256) void gemm_mfma(const void* __restrict__ Ap,
                                                 const unsigned short* __restrict__ Wt,
                                                 unsigned short* __restrict__ Cb,
                                                 const float* __restrict__ fscale) {
  int wv   = threadIdx.x >> 6;
  int lane = threadIdx.x & 63;
  int l15  = lane & 15, lg = lane >> 4;
  size_t rowbase = (size_t)blockIdx.x * 128 + wv * 32;

  short8 afrag[2][4];
#pragma unroll
  for (int rg = 0; rg < 2; ++rg) {
    size_t row = rowbase + rg * 16 + l15;
    float fs = (fscale != nullptr) ? fscale[row] : 1.0f;
#pragma unroll
    for (int c = 0; c < 4; ++c) {
      int k0 = c * 32 + lg * 8;
      short8 a;
      if (ABF16) {
        const unsigned short* p = (const unsigned short*)Ap + row * 128 + k0;
        uint4 u = *(const uint4*)p;
        unsigned w[4] = {u.x, u.y, u.z, u.w};
#pragma unroll
        for (int q = 0; q < 4; ++q) {
          a[2 * q]     = (short)f2bf(bf2f((unsigned short)(w[q] & 0xFFFFu)) * fs);
          a[2 * q + 1] = (short)f2bf(bf2f((unsigned short)(w[q] >> 16)) * fs);
        }
      } else {
        const float* p = (const float*)Ap + row * 128 + k0;
        float4 v0 = *(const float4*)p;
        float4 v1 = *(const float4*)(p + 4);
        a[0] = (short)f2bf(v0.x * fs); a[1] = (short)f2bf(v0.y * fs);
        a[2] = (short)f2bf(v0.z * fs); a[3] = (short)f2bf(v0.w * fs);
        a[4] = (short)f2bf(v1.x * fs); a[5] = (short)f2bf(v1.y * fs);
        a[6] = (short)f2bf(v1.z * fs); a[7] = (short)f2bf(v1.w * fs);
      }
      afrag[rg][c] = a;
    }
  }

#pragma unroll
  for (int t = 0; t < 8; ++t) {
    int col = t * 16 + l15;
    short8 bfrag[4];
#pragma unroll
    for (int c = 0; c < 4; ++c)
      bfrag[c] = *(const short8*)(Wt + col * 128 + c * 32 + lg * 8);

    floatx4 acc0 = {0.f, 0.f, 0.f, 0.f};
    floatx4 acc1 = {0.f, 0.f, 0.f, 0.f};
#pragma unroll
    for (int c = 0; c < 4; ++c) {
      acc0 = __builtin_amdgcn_mfma_f32_16x16x32_bf16(afrag[0][c], bfrag[c], acc0, 0, 0, 0);
      acc1 = __builtin_amdgcn_mfma_f32_16x16x32_bf16(afrag[1][c], bfrag[c], acc1, 0, 0, 0);
    }
#pragma unroll
    for (int r = 0; r < 4; ++r) {
      size_t row0 = rowbase + lg * 4 + r;
      size_t row1 = rowbase + 16 + lg * 4 + r;
      Cb[row0 * 128 + t * 16 + l15] = f2bf(acc0[r]);
      Cb[row1 * 128 + t * 16 + l15] = f2bf(acc1[r]);
    }
  }
}

// ---------------------------------------------------------------------------
// layer-1 dinv: all nodes live, deg = in-degree + 1 (self loop)
// ---------------------------------------------------------------------------
__global__ __launch_bounds__(256) void deg_init(const int* __restrict__ offs,
                                                float* __restrict__ dinv) {
  int g = blockIdx.x * 256 + threadIdx.x;      // < B*N
  int b = g >> 13, n = g & (N - 1);
  int d = offs[b * (N + 1) + n + 1] - offs[b * (N + 1) + n];
  dinv[g] = rsqrtf((float)d + 1.0f);
}

// ---------------------------------------------------------------------------
// dinv with mask: 16 lanes per node, lane-parallel mask gather.
// ---------------------------------------------------------------------------
__global__ __launch_bounds__(256) void deg_masked(const float* __restrict__ mask,
                                                  const int* __restrict__ offs,
                                                  const int* __restrict__ csr,
                                                  float* __restrict__ dinv) {
  int grp = threadIdx.x >> 4;                  // 16 nodes per block
  int gl  = threadIdx.x & 15;
  int nid = blockIdx.x * 16 + grp;             // < B*N
  int b = nid >> 13, n = nid & (N - 1);
  float m = mask[nid];
  float s = 0.0f;
  if (m > 0.0f) {
    int o0 = offs[b * (N + 1) + n], o1 = offs[b * (N + 1) + n + 1];
    const int* cs = csr + (size_t)b * E;
    const float* mb = mask + b * N;
    for (int base = o0; base < o1; base += 16)
      if (base + gl < o1) s += mb[cs[base + gl]];
  }
#pragma unroll
  for (int d = 8; d > 0; d >>= 1) s += __shfl_xor(s, d, 16);
  if (gl == 0) dinv[nid] = (m > 0.0f) ? rsqrtf(s + 1.0f) : 0.0f;
}

// ---------------------------------------------------------------------------
// GCN aggregation v3: one wave per node. Edge metadata in SGPRs via
// v_readlane (wave-uniform idx) -> saddr-form row gathers with zero per-edge
// VALU address math; w is an SGPR FMA operand. Dead srcs are branch-free:
// their index is cselected to row 0 with w=0. 16-deep load batches, dual
// accumulators. XCD-swizzled block->graph mapping (2 graphs per XCD).
// ---------------------------------------------------------------------------
template <bool ALL_LIVE>
__global__ __launch_bounds__(256) void gcn_agg3(
    const unsigned* __restrict__ tmp, const float* __restrict__ dinv,
    const int* __restrict__ offs, const int* __restrict__ csr,
    const float* __restrict__ bias, unsigned* __restrict__ hout,
    const float* __restrict__ wrel, const float* __restrict__ wroot,
    float* __restrict__ rr, float* __restrict__ tt) {
  int blk = blockIdx.x;
  int xcd = blk & 7;
  int j   = blk >> 3;                      // 0..4095
  int b   = xcd * 2 + (j >> 11);           // 2 graphs per XCD
  int n   = (j & 2047) * 4 + (threadIdx.x >> 6);
  int wid = b * N + n;
  int lane = threadIdx.x & 63;

  float dv = rdlane_f(dinv[wid], 0);       // wave-uniform -> SGPR
  unsigned* hrow = hout + (size_t)wid * 64;

  if (!ALL_LIVE && dv <= 0.0f) {           // dead destination: zeros only
    hrow[lane] = 0u;
    if (rr != nullptr && lane == 0) { rr[wid] = 0.0f; tt[wid] = 0.0f; }
    return;
  }

  const unsigned* tmpb = tmp + (((size_t)b << 13) << 6);
  const float* dvb = dinv + (b << 13);
  const int*   cs  = csr + (size_t)b * E;

  float2 accA, accB;
  {
    const unsigned* selfp = tmpb + ((unsigned)n << 6);
    unsigned u = selfp[lane];
    accA.x = dv * __uint_as_float(u << 16);
    accA.y = dv * __uint_as_float(u & 0xFFFF0000u);
    accB.x = 0.0f; accB.y = 0.0f;
  }

  int nbase = b * (N + 1) + n;
  int o0 = __builtin_amdgcn_readfirstlane(offs[nbase]);
  int o1 = __builtin_amdgcn_readfirstlane(offs[nbase + 1]);

  for (int base = o0; base < o1; base += 64) {
    int nv = o1 - base; if (nv > 64) nv = 64;
    int sl = 0; float wl = 0.0f;
    if (lane < nv) {
      sl = cs[base + lane];
      wl = dvb[sl];                          // 0 for dead sources
      if (!ALL_LIVE && wl <= 0.0f) sl = 0;   // branch-free: gather row 0, w=0
    }

    for (int i0 = 0; i0 < nv; i0 += 16) {
      unsigned uu[16]; float wq[16];
#pragma unroll
      for (int q = 0; q < 16; ++q) {
        int idx = i0 + q;                    // < 64 always; pads have w=0,s=0
        int   sq = rdlane_i(sl, idx);        // SGPR
        wq[q]    = rdlane_f(wl, idx);        // SGPR
        const unsigned* rowp = tmpb + ((unsigned)sq << 6);  // uniform base
        uu[q] = rowp[lane];                  // saddr + lane*4 voffset
      }
#pragma unroll
      for (int q = 0; q < 16; ++q) {
        float lo = __uint_as_float(uu[q] << 16);
        float hi = __uint_as_float(uu[q] & 0xFFFF0000u);
        if (q & 1) { accB.x += wq[q] * lo; accB.y += wq[q] * hi; }
        else       { accA.x += wq[q] * lo; accA.y += wq[q] * hi; }
      }
    }
  }

  float2 acc = {accA.x + accB.x, accA.y + accB.y};
  const float2 bb = *(const float2*)(bias + lane * 2);
  float2 outv;
  outv.x = fmaxf(dv * acc.x + bb.x, 0.0f);
  outv.y = fmaxf(dv * acc.y + bb.y, 0.0f);
  hrow[lane] = ((unsigned)f2bf(outv.y) << 16) | (unsigned)f2bf(outv.x);

  if (rr != nullptr) {                        // fused pool dots r=h.wrel t=h.wroot
    const float2 wr = *(const float2*)(wrel + lane * 2);
    const float2 wo = *(const float2*)(wroot + lane * 2);
    float pr = outv.x * wr.x + outv.y * wr.y;
    float pt = outv.x * wo.x + outv.y * wo.y;
#pragma unroll
    for (int d = 32; d > 0; d >>= 1) {
      pr += __shfl_down(pr, d);
      pt += __shfl_down(pt, d);
    }
    if (lane == 0) { rr[wid] = pr; tt[wid] = pt; }
  }
}

// ---------------------------------------------------------------------------
// pool score: score[n] = mask[n]*(sum_in r[src] + t[n] + b); 16 lanes/node.
// ---------------------------------------------------------------------------
__global__ __launch_bounds__(256) void score_agg(const float* __restrict__ r,
                                                 const float* __restrict__ t,
                                                 const float* __restrict__ pb,
                                                 const float* __restrict__ mask,
                                                 const int* __restrict__ offs,
                                                 const int* __restrict__ csr,
                                                 float* __restrict__ score) {
  int grp = threadIdx.x >> 4;
  int gl  = threadIdx.x & 15;
  int nid = blockIdx.x * 16 + grp;
  int b = nid >> 13, n = nid & (N - 1);
  bool live = (mask == nullptr) || (mask[nid] > 0.0f);
  float s = 0.0f;
  if (live) {
    int o0 = offs[b * (N + 1) + n], o1 = offs[b * (N + 1) + n + 1];
    const int* cs = csr + (size_t)b * E;
    const float* rb = r + b * N;
    for (int base = o0; base < o1; base += 16)
      if (base + gl < o1) s += rb[cs[base + gl]];   // r==0 for dead srcs
  }
#pragma unroll
  for (int d = 8; d > 0; d >>= 1) s += __shfl_xor(s, d, 16);
  if (gl == 0) score[nid] = live ? (s + t[nid] + pb[0]) : 0.0f;
}

// ---------------------------------------------------------------------------
// top-k via radix select; index-ordered ties. Keys cached in LDS (one global
// read); per-pass bucket pick via parallel suffix scan (was serial 256-walk).
// Writes new mask AND fscale = tanh(score)*new_mask.
// ---------------------------------------------------------------------------
__device__ __forceinline__ unsigned fkey(float s, float m) {
  if (m <= 0.0f) return 0u;
  unsigned u = __float_as_uint(s);
  return (u & 0x80000000u) ? ~u : (u | 0x80000000u);
}

__global__ __launch_bounds__(1024) void topk_kernel(const float* __restrict__ score,
                                                    const float* __restrict__ mkin,
                                                    float* __restrict__ mkout,
                                                    float* __restrict__ fscale,
                                                    int k) {
  int b = blockIdx.x, tid = threadIdx.x;
  const float* sc = score + b * N;
  float* mk = mkout + b * N;
  float* fs = fscale + b * N;
  __shared__ unsigned keyb[N];        // 32 KB
  __shared__ int hist[256];
  __shared__ int sbuf[1024];
  __shared__ unsigned sh_prefix;
  __shared__ int sh_kneed;

  for (int i = tid; i < N; i += 1024) {
    float m = (mkin == nullptr) ? 1.0f : mkin[b * N + i];
    keyb[i] = fkey(sc[i], m);
  }
  __syncthreads();

  unsigned prefix = 0, hm = 0;
  int kneed = k;
  for (int shift = 24; shift >= 0; shift -= 8) {
    if (tid < 256) hist[tid] = 0;
    __syncthreads();
    for (int i = tid; i < N; i += 1024) {
      unsigned key = keyb[i];
      if ((key & hm) == prefix) atomicAdd(&hist[(key >> shift) & 255], 1);
    }
    __syncthreads();
    // suffix sums over 256 bins: sbuf[i] = sum_{j>=i} hist[j]
    if (tid < 256) sbuf[tid] = hist[tid];
    __syncthreads();
    for (int off = 1; off < 256; off <<= 1) {
      int v = (tid < 256 && tid + off < 256) ? sbuf[tid + off] : 0;
      __syncthreads();
      if (tid < 256) sbuf[tid] += v;
      __syncthreads();
    }
    if (tid < 256) {
      int ge = sbuf[tid];
      int gt = (tid < 255) ? sbuf[tid + 1] : 0;
      if (ge >= kneed && gt < kneed) {
        sh_prefix = prefix | ((unsigned)tid << shift);
        sh_kneed = kneed - gt;
      }
    }
    __syncthreads();
    prefix = sh_prefix;
    kneed = sh_kneed;
    hm |= (0xFFu << shift);
    __syncthreads();
  }

  unsigned T = prefix;              // key of the k-th largest
  int base = tid * 8;
  unsigned keys[8];
  int eqf[8];
  int cnt = 0;
#pragma unroll
  for (int q = 0; q < 8; ++q) {
    keys[q] = keyb[base + q];
    eqf[q] = (keys[q] == T) ? 1 : 0;
    cnt += eqf[q];
  }
  sbuf[tid] = cnt; __syncthreads();
  for (int off = 1; off < 1024; off <<= 1) {
    int x = (tid >= off) ? sbuf[tid - off] : 0;
    __syncthreads();
    sbuf[tid] += x;
    __syncthreads();
  }
  int ex = sbuf[tid] - cnt;         // rank base among ties (index order)
#pragma unroll
  for (int q = 0; q < 8; ++q) {
    bool sel = (keys[q] > T) || (eqf[q] && (ex < kneed));
    ex += eqf[q];
    mk[base + q] = sel ? 1.0f : 0.0f;
    fs[base + q] = sel ? tanhf(sc[base + q]) : 0.0f;
  }
}

// ---------------------------------------------------------------------------
// readout partials (bf16 h) + head MLP + log_softmax
// ---------------------------------------------------------------------------
__global__ __launch_bounds__(256) void readout(const unsigned short* __restrict__ h,
                                               float* __restrict__ part) {
  int b = blockIdx.x, c = blockIdx.y;
  int tid = threadIdx.x;
  int f = tid & 127, half = tid >> 7;
  float acc = 0.0f;
  for (int n = c * 256 + half; n < (c + 1) * 256; n += 2)
    acc += bf2f(h[((size_t)b * N + n) * 128 + f]);
  __shared__ float red[256];
  red[tid] = acc; __syncthreads();
  if (half == 0) part[((size_t)b * 32 + c) * 128 + f] = red[f] + red[f + 128];
}

__global__ __launch_bounds__(128) void head(const float* __restrict__ part,
                                            const float* __restrict__ l1w,
                                            const float* __restrict__ l1b,
                                            const float* __restrict__ l2w,
                                            const float* __restrict__ l2b,
                                            float* __restrict__ out) {
  int b = blockIdx.x, f = threadIdx.x;
  float g = 0.0f;
  for (int c = 0; c < 32; ++c) g += part[((size_t)b * 32 + c) * 128 + f];
  g *= (1.0f / (float)K2);
  __shared__ float gs[128], hh[128], lg[10];
  gs[f] = g; __syncthreads();
  float a = l1b[f];
  for (int kk = 0; kk < 128; ++kk) a += gs[kk] * l1w[kk * 128 + f];
  hh[f] = fmaxf(a, 0.0f); __syncthreads();
  if (f < 10) {
    float l = l2b[f];
    for (int j = 0; j < 128; ++j) l += hh[j] * l2w[j * 10 + f];
    lg[f] = l;
  }
  __syncthreads();
  if (f == 0) {
    float m = lg[0];
    for (int c = 1; c < 10; ++c) m = fmaxf(m, lg[c]);
    float s = 0.0f;
    for (int c = 0; c < 10; ++c) s += expf(lg[c] - m);
    float lse = m + logf(s);
    for (int c = 0; c < 10; ++c) out[b * 10 + c] = lg[c] - lse;
  }
}

// ---------------------------------------------------------------------------
extern "C" void kernel_launch(void* const* d_in, const int* in_sizes, int n_in,
                              void* d_out, int out_size, void* d_ws, size_t ws_size,
                              hipStream_t stream) {
  (void)in_sizes; (void)n_in; (void)out_size; (void)ws_size;
  const float* x       = (const float*)d_in[0];
  const int*   ei      = (const int*)d_in[1];
  const float* W1      = (const float*)d_in[2];
  const float* b1      = (const float*)d_in[3];
  const float* p1_wrel = (const float*)d_in[4];
  const float* p1_wroot= (const float*)d_in[5];
  const float* p1_b    = (const float*)d_in[6];
  const float* W2      = (const float*)d_in[7];
  const float* b2      = (const float*)d_in[8];
  const float* p2_wrel = (const float*)d_in[9];
  const float* p2_wroot= (const float*)d_in[10];
  const float* p2_b    = (const float*)d_in[11];
  const float* W3      = (const float*)d_in[12];
  const float* b3      = (const float*)d_in[13];
  const float* l1w     = (const float*)d_in[14];
  const float* l1b     = (const float*)d_in[15];
  const float* l2w     = (const float*)d_in[16];
  const float* l2b     = (const float*)d_in[17];
  float* out = (float*)d_out;

  // workspace carve-up
  char* p = (char*)d_ws;
  auto alloc = [&](size_t bytes) {
    char* r = p;
    p += ((bytes + 255) & ~(size_t)255);
    return r;
  };
  unsigned short* h   = (unsigned short*)alloc((size_t)B * N * H * 2);   // bf16
  unsigned short* tmp = (unsigned short*)alloc((size_t)B * N * H * 2);   // bf16
  int*   offs   = (int*)alloc((size_t)B * (N + 1) * 4);
  int*   cur    = (int*)alloc((size_t)B * N * 4);
  int*   csr    = (int*)alloc((size_t)B * E * 4);
  float* dinv   = (float*)alloc((size_t)B * N * 4);
  float* mask   = (float*)alloc((size_t)B * N * 4);
  float* rr     = (float*)alloc((size_t)B * N * 4);
  float* tt     = (float*)alloc((size_t)B * N * 4);
  float* score  = (float*)alloc((size_t)B * N * 4);
  float* fscale = (float*)alloc((size_t)B * N * 4);
  float* part   = (float*)alloc((size_t)B * 32 * H * 4);
  unsigned short* Wt1 = (unsigned short*)alloc(128 * 128 * 2);
  unsigned short* Wt2 = (unsigned short*)alloc(128 * 128 * 2);
  unsigned short* Wt3 = (unsigned short*)alloc(128 * 128 * 2);

  // CSR build + weight prep
  hipMemsetAsync(cur, 0, (size_t)B * N * 4, stream);
  count_edges<<<B * E / 256, 256, 0, stream>>>(ei, cur);
  scan_offsets<<<B, 1024, 0, stream>>>(cur, offs);
  fill_csr<<<B * E / 256, 256, 0, stream>>>(ei, cur, csr);
  prep_wt<<<1, 256, 0, stream>>>(W1, Wt1);
  prep_wt<<<1, 256, 0, stream>>>(W2, Wt2);
  prep_wt<<<1, 256, 0, stream>>>(W3, Wt3);

  // ---- layer 1 + pool 1 (all nodes live)
  gemm_mfma<false><<<(B * N) / 128, 256, 0, stream>>>(x, Wt1, tmp, nullptr);
  deg_init<<<B * N / 256, 256, 0, stream>>>(offs, dinv);
  gcn_agg3<true><<<B * N / 4, 256, 0, stream>>>((const unsigned*)tmp, dinv, offs, csr, b1,
                                                (unsigned*)h, p1_wrel, p1_wroot, rr, tt);
  score_agg<<<B * N / 16, 256, 0, stream>>>(rr, tt, p1_b, nullptr, offs, csr, score);
  topk_kernel<<<B, 1024, 0, stream>>>(score, nullptr, mask, fscale, K1);

  // ---- layer 2 + pool 2 (pool-1 scaling fused into GEMM A-frag load)
  gemm_mfma<true><<<(B * N) / 128, 256, 0, stream>>>(h, Wt2, tmp, fscale);
  deg_masked<<<B * N / 16, 256, 0, stream>>>(mask, offs, csr, dinv);
  gcn_agg3<false><<<B * N / 4, 256, 0, stream>>>((const unsigned*)tmp, dinv, offs, csr, b2,
                                                 (unsigned*)h, p2_wrel, p2_wroot, rr, tt);
  score_agg<<<B * N / 16, 256, 0, stream>>>(rr, tt, p2_b, mask, offs, csr, score);
  topk_kernel<<<B, 1024, 0, stream>>>(score, mask, mask, fscale, K2);

  // ---- layer 3
  gemm_mfma<true><<<(B * N) / 128, 256, 0, stream>>>(h, Wt3, tmp, fscale);
  deg_masked<<<B * N / 16, 256, 0, stream>>>(mask, offs, csr, dinv);
  gcn_agg3<false><<<B * N / 4, 256, 0, stream>>>((const unsigned*)tmp, dinv, offs, csr, b3,
                                                 (unsigned*)h, nullptr, nullptr, nullptr, nullptr);

  // ---- readout + head
  readout<<<dim3(B, 32), 256, 0, stream>>>(h, part);
  head<<<B, 128, 0, stream>>>(part, l1w, l1b, l2w, l2b, out);
}

// Round 5
// 437.736 us; speedup vs baseline: 2.5026x; 1.3616x over previous
//
#include <hip/hip_runtime.h>
#include <hip/hip_bf16.h>
#include <math.h>

// Problem constants
constexpr int B  = 16;
constexpr int N  = 8192;     // 2^13
constexpr int E  = 131072;   // 2^17
constexpr int H  = 128;
constexpr int K1 = 4096;
constexpr int K2 = 2048;

constexpr int CHUNKS = 16;         // edge chunks per graph (8192 edges each)
constexpr int NBK    = 16;         // dst buckets (dst>>9, 512 nodes each)
constexpr int FCAP   = 12288;      // final_scatter LDS capacity (avg 8192, +46 sigma)

typedef __attribute__((ext_vector_type(8))) short short8;
typedef __attribute__((ext_vector_type(4))) float floatx4;

__device__ __forceinline__ unsigned short f2bf(float f) {
  unsigned u = __float_as_uint(f);
  return (unsigned short)((u + 0x7FFFu + ((u >> 16) & 1u)) >> 16);  // RNE
}
__device__ __forceinline__ float bf2f(unsigned short s) {
  return __uint_as_float(((unsigned)s) << 16);
}
__device__ __forceinline__ int rdlane_i(int v, int l) {
  return __builtin_amdgcn_readlane(v, l);
}
__device__ __forceinline__ float rdlane_f(float v, int l) {
  return __uint_as_float((unsigned)__builtin_amdgcn_readlane((int)__float_as_uint(v), l));
}

// ---------------------------------------------------------------------------
// CSR build, pass 1: per-(graph,chunk) histogram over 16 dst-buckets.
// All reads coalesced; writes are 16 ints per block.
// ---------------------------------------------------------------------------
__global__ __launch_bounds__(256) void hist_pass(const int* __restrict__ ei,
                                                 int* __restrict__ bchist) {
  int blk = blockIdx.x;                 // B*CHUNKS = 256
  int b = blk >> 4, c = blk & 15;
  __shared__ int h16[NBK];
  if (threadIdx.x < NBK) h16[threadIdx.x] = 0;
  __syncthreads();
  const int* dstp = ei + (size_t)b * 2 * E + E + c * 8192;
  for (int i = 0; i < 32; ++i) {
    int dst = dstp[i * 256 + threadIdx.x];
    atomicAdd(&h16[dst >> 9], 1);
  }
  __syncthreads();
  if (threadIdx.x < NBK) bchist[(blk << 4) + threadIdx.x] = h16[threadIdx.x];
}

// ---------------------------------------------------------------------------
// CSR build, pass 2: per-graph bucket bases + per-(chunk,bucket) cursors.
// Gives every bin_scatter block an exclusive output region (no atomics).
// ---------------------------------------------------------------------------
__global__ __launch_bounds__(256) void bucket_scan(const int* __restrict__ bchist,
                                                   int* __restrict__ cursor,
                                                   int* __restrict__ bbase) {
  int b = blockIdx.x;                   // B = 16
  int tid = threadIdx.x;                // 256 = CHUNKS*NBK
  int c = tid >> 4, k = tid & 15;
  __shared__ int arr[CHUNKS][NBK];
  __shared__ int base[NBK + 1];
  arr[c][k] = bchist[((b * CHUNKS + c) << 4) + k];
  __syncthreads();
  if (tid == 0) {
    int run = 0;
    for (int kk = 0; kk < NBK; ++kk) {
      base[kk] = run;
      int t = 0;
      for (int cc = 0; cc < CHUNKS; ++cc) t += arr[cc][kk];
      run += t;
    }
    base[NBK] = run;                    // == E
  }
  __syncthreads();
  int pre = 0;
  for (int cc = 0; cc < c; ++cc) pre += arr[cc][k];
  cursor[((b * CHUNKS + c) << 4) + k] = base[k] + pre;
  if (tid < NBK + 1) bbase[b * (NBK + 1) + tid] = base[tid];
}

// ---------------------------------------------------------------------------
// CSR build, pass 3: bin edges by bucket. LDS-staged, per-bucket segments
// flushed contiguously to private cursor regions -> sequential HBM writes.
// Packs (dst&511)<<13 | src into u32.
// ---------------------------------------------------------------------------
__global__ __launch_bounds__(256) void bin_scatter(const int* __restrict__ ei,
                                                   const int* __restrict__ cursor,
                                                   unsigned* __restrict__ pbuf) {
  int blk = blockIdx.x;                 // B*CHUNKS = 256
  int b = blk >> 4, c = blk & 15;
  __shared__ int gcur[NBK], lcnt[NBK], lfill[NBK];
  __shared__ int lbase[NBK + 1];
  __shared__ unsigned sbuf[2048];
  int tid = threadIdx.x;
  if (tid < NBK) gcur[tid] = cursor[(blk << 4) + tid];
  const int* srcp = ei + (size_t)b * 2 * E + c * 8192;
  const int* dstp = srcp + E;
  unsigned* pb = pbuf + (size_t)b * E;

  for (int sc = 0; sc < 4; ++sc) {      // 4 subchunks of 2048
    if (tid < NBK) { lcnt[tid] = 0; lfill[tid] = 0; }
    __syncthreads();
    int s8[8], d8[8];
#pragma unroll
    for (int q = 0; q < 8; ++q) {
      int i = sc * 2048 + q * 256 + tid;
      s8[q] = srcp[i]; d8[q] = dstp[i];
      atomicAdd(&lcnt[d8[q] >> 9], 1);
    }
    __syncthreads();
    if (tid == 0) {
      int run = 0;
      for (int k = 0; k < NBK; ++k) { lbase[k] = run; run += lcnt[k]; }
      lbase[NBK] = run;                 // 2048
    }
    __syncthreads();
#pragma unroll
    for (int q = 0; q < 8; ++q) {
      int k = d8[q] >> 9;
      int idx = atomicAdd(&lfill[k], 1);
      sbuf[lbase[k] + idx] = ((unsigned)(d8[q] & 511) << 13) | (unsigned)s8[q];
    }
    __syncthreads();
    for (int i = tid; i < 2048; i += 256) {   // ordered, segment-contiguous flush
      int k = 0;
      while (lbase[k + 1] <= i) ++k;
      pb[gcur[k] + (i - lbase[k])] = sbuf[i];
    }
    __syncthreads();
    if (tid < NBK) gcur[tid] += lcnt[tid];
    __syncthreads();
  }
}

// ---------------------------------------------------------------------------
// CSR build, pass 4: one block per (graph,bucket). Per-node count -> scan ->
// in-LDS scatter -> coalesced csr write. Also writes offs and layer-1 dinv.
// ---------------------------------------------------------------------------
__global__ __launch_bounds__(256) void final_scatter(const unsigned* __restrict__ pbuf,
                                                     const int* __restrict__ bbase,
                                                     int* __restrict__ csr,
                                                     int* __restrict__ offs,
                                                     float* __restrict__ dinv1) {
  int blk = blockIdx.x;                 // B*NBK = 256
  int b = blk >> 4, k = blk & 15;
  __shared__ int ncnt[512], nbase[512], nfill[512];
  __shared__ int sred[256];
  __shared__ unsigned sbuf[FCAP];
  int tid = threadIdx.x;
  int gbase = bbase[b * (NBK + 1) + k];
  int gend  = bbase[b * (NBK + 1) + k + 1];
  int cnt = gend - gbase;
  const unsigned* pb = pbuf + (size_t)b * E + gbase;

  for (int i = tid; i < 512; i += 256) { ncnt[i] = 0; nfill[i] = 0; }
  __syncthreads();
  for (int i = tid; i < cnt; i += 256) atomicAdd(&ncnt[pb[i] >> 13], 1);
  __syncthreads();
  // exclusive scan over 512 node counts (2 per thread)
  int v0 = ncnt[2 * tid], v1 = ncnt[2 * tid + 1];
  int s = v0 + v1;
  sred[tid] = s;
  __syncthreads();
  for (int off = 1; off < 256; off <<= 1) {
    int x = (tid >= off) ? sred[tid - off] : 0;
    __syncthreads();
    sred[tid] += x;
    __syncthreads();
  }
  int ex = sred[tid] - s;
  nbase[2 * tid] = ex;
  nbase[2 * tid + 1] = ex + v0;
  __syncthreads();
  for (int i = tid; i < 512; i += 256) {
    int node = k * 512 + i;
    offs[b * (N + 1) + node] = gbase + nbase[i];
    dinv1[b * N + node] = rsqrtf((float)ncnt[i] + 1.0f);  // all-live layer-1 dinv
  }
  if (k == 15 && tid == 0) offs[b * (N + 1) + N] = E;
  __syncthreads();
  for (int i = tid; i < cnt; i += 256) {
    unsigned pk = pb[i];
    int node = pk >> 13;
    int idx = atomicAdd(&nfill[node], 1);
    sbuf[nbase[node] + idx] = pk & 8191u;
  }
  __syncthreads();
  int* co = csr + (size_t)b * E + gbase;
  for (int i = tid; i < cnt; i += 256) co[i] = (int)sbuf[i];
}

// ---------------------------------------------------------------------------
// W[128][128] fp32 -> Wt[128][128] bf16 transposed, 3 weights in one launch
// ---------------------------------------------------------------------------
__global__ __launch_bounds__(256) void prep_wt3(const float* __restrict__ W1,
                                                const float* __restrict__ W2,
                                                const float* __restrict__ W3,
                                                unsigned short* __restrict__ Wt) {
  const float* W = (blockIdx.x == 0) ? W1 : (blockIdx.x == 1) ? W2 : W3;
  unsigned short* o = Wt + blockIdx.x * 128 * 128;
  for (int i = threadIdx.x; i < 128 * 128; i += 256) {
    int k = i >> 7, n = i & 127;
    o[n * 128 + k] = f2bf(W[i]);
  }
}

// ---------------------------------------------------------------------------
// MFMA GEMM: C[M,128](bf16) = (A[M,128]*fscale) @ W, W given as Wt[n][k] bf16.
// 256 thr = 4 waves; wave owns 32 rows; no LDS, no barriers.
// ---------------------------------------------------------------------------
template <bool ABF16>
__global__ __launch_bounds__(256) void gemm_mfma(const void* __restrict__ Ap,
                                                 const unsigned short* __restrict__ Wt,
                                                 unsigned short* __restrict__ Cb,
                                                 const float* __restrict__ fscale) {
  int wv   = threadIdx.x >> 6;
  int lane = threadIdx.x & 63;
  int l15  = lane & 15, lg = lane >> 4;
  size_t rowbase = (size_t)blockIdx.x * 128 + wv * 32;

  short8 afrag[2][4];
#pragma unroll
  for (int rg = 0; rg < 2; ++rg) {
    size_t row = rowbase + rg * 16 + l15;
    float fs = (fscale != nullptr) ? fscale[row] : 1.0f;
#pragma unroll
    for (int c = 0; c < 4; ++c) {
      int k0 = c * 32 + lg * 8;
      short8 a;
      if (ABF16) {
        const unsigned short* p = (const unsigned short*)Ap + row * 128 + k0;
        uint4 u = *(const uint4*)p;
        unsigned w[4] = {u.x, u.y, u.z, u.w};
#pragma unroll
        for (int q = 0; q < 4; ++q) {
          a[2 * q]     = (short)f2bf(bf2f((unsigned short)(w[q] & 0xFFFFu)) * fs);
          a[2 * q + 1] = (short)f2bf(bf2f((unsigned short)(w[q] >> 16)) * fs);
        }
      } else {
        const float* p = (const float*)Ap + row * 128 + k0;
        float4 v0 = *(const float4*)p;
        float4 v1 = *(const float4*)(p + 4);
        a[0] = (short)f2bf(v0.x * fs); a[1] = (short)f2bf(v0.y * fs);
        a[2] = (short)f2bf(v0.z * fs); a[3] = (short)f2bf(v0.w * fs);
        a[4] = (short)f2bf(v1.x * fs); a[5] = (short)f2bf(v1.y * fs);
        a[6] = (short)f2bf(v1.z * fs); a[7] = (short)f2bf(v1.w * fs);
      }
      afrag[rg][c] = a;
    }
  }

#pragma unroll
  for (int t = 0; t < 8; ++t) {
    int col = t * 16 + l15;
    short8 bfrag[4];
#pragma unroll
    for (int c = 0; c < 4; ++c)
      bfrag[c] = *(const short8*)(Wt + col * 128 + c * 32 + lg * 8);

    floatx4 acc0 = {0.f, 0.f, 0.f, 0.f};
    floatx4 acc1 = {0.f, 0.f, 0.f, 0.f};
#pragma unroll
    for (int c = 0; c < 4; ++c) {
      acc0 = __builtin_amdgcn_mfma_f32_16x16x32_bf16(afrag[0][c], bfrag[c], acc0, 0, 0, 0);
      acc1 = __builtin_amdgcn_mfma_f32_16x16x32_bf16(afrag[1][c], bfrag[c], acc1, 0, 0, 0);
    }
#pragma unroll
    for (int r = 0; r < 4; ++r) {
      size_t row0 = rowbase + lg * 4 + r;
      size_t row1 = rowbase + 16 + lg * 4 + r;
      Cb[row0 * 128 + t * 16 + l15] = f2bf(acc0[r]);
      Cb[row1 * 128 + t * 16 + l15] = f2bf(acc1[r]);
    }
  }
}

// ---------------------------------------------------------------------------
// dinv with mask: 16 lanes per node, lane-parallel mask gather.
// ---------------------------------------------------------------------------
__global__ __launch_bounds__(256) void deg_masked(const float* __restrict__ mask,
                                                  const int* __restrict__ offs,
                                                  const int* __restrict__ csr,
                                                  float* __restrict__ dinv) {
  int grp = threadIdx.x >> 4;                  // 16 nodes per block
  int gl  = threadIdx.x & 15;
  int nid = blockIdx.x * 16 + grp;             // < B*N
  int b = nid >> 13, n = nid & (N - 1);
  float m = mask[nid];
  float s = 0.0f;
  if (m > 0.0f) {
    int o0 = offs[b * (N + 1) + n], o1 = offs[b * (N + 1) + n + 1];
    const int* cs = csr + (size_t)b * E;
    const float* mb = mask + b * N;
    for (int base = o0; base < o1; base += 16)
      if (base + gl < o1) s += mb[cs[base + gl]];
  }
#pragma unroll
  for (int d = 8; d > 0; d >>= 1) s += __shfl_xor(s, d, 16);
  if (gl == 0) dinv[nid] = (m > 0.0f) ? rsqrtf(s + 1.0f) : 0.0f;
}

// ---------------------------------------------------------------------------
// GCN aggregation v3: one wave per node. Edge metadata in SGPRs via
// v_readlane -> saddr-form row gathers; dead srcs branch-free (row 0, w=0).
// 16-deep load batches, dual accumulators, XCD-swizzled block->graph map.
// ---------------------------------------------------------------------------
template <bool ALL_LIVE>
__global__ __launch_bounds__(256) void gcn_agg3(
    const unsigned* __restrict__ tmp, const float* __restrict__ dinv,
    const int* __restrict__ offs, const int* __restrict__ csr,
    const float* __restrict__ bias, unsigned* __restrict__ hout,
    const float* __restrict__ wrel, const float* __restrict__ wroot,
    float* __restrict__ rr, float* __restrict__ tt) {
  int blk = blockIdx.x;
  int xcd = blk & 7;
  int j   = blk >> 3;                      // 0..4095
  int b   = xcd * 2 + (j >> 11);           // 2 graphs per XCD
  int n   = (j & 2047) * 4 + (threadIdx.x >> 6);
  int wid = b * N + n;
  int lane = threadIdx.x & 63;

  float dv = rdlane_f(dinv[wid], 0);       // wave-uniform -> SGPR
  unsigned* hrow = hout + (size_t)wid * 64;

  if (!ALL_LIVE && dv <= 0.0f) {           // dead destination: zeros only
    hrow[lane] = 0u;
    if (rr != nullptr && lane == 0) { rr[wid] = 0.0f; tt[wid] = 0.0f; }
    return;
  }

  const unsigned* tmpb = tmp + (((size_t)b << 13) << 6);
  const float* dvb = dinv + (b << 13);
  const int*   cs  = csr + (size_t)b * E;

  float2 accA, accB;
  {
    const unsigned* selfp = tmpb + ((unsigned)n << 6);
    unsigned u = selfp[lane];
    accA.x = dv * __uint_as_float(u << 16);
    accA.y = dv * __uint_as_float(u & 0xFFFF0000u);
    accB.x = 0.0f; accB.y = 0.0f;
  }

  int nbase = b * (N + 1) + n;
  int o0 = __builtin_amdgcn_readfirstlane(offs[nbase]);
  int o1 = __builtin_amdgcn_readfirstlane(offs[nbase + 1]);

  for (int base = o0; base < o1; base += 64) {
    int nv = o1 - base; if (nv > 64) nv = 64;
    int sl = 0; float wl = 0.0f;
    if (lane < nv) {
      sl = cs[base + lane];
      wl = dvb[sl];                          // 0 for dead sources
      if (!ALL_LIVE && wl <= 0.0f) sl = 0;   // branch-free: gather row 0, w=0
    }

    for (int i0 = 0; i0 < nv; i0 += 16) {
      unsigned uu[16]; float wq[16];
#pragma unroll
      for (int q = 0; q < 16; ++q) {
        int idx = i0 + q;                    // < 64 always; pads have w=0,s=0
        int   sq = rdlane_i(sl, idx);        // SGPR
        wq[q]    = rdlane_f(wl, idx);        // SGPR
        const unsigned* rowp = tmpb + ((unsigned)sq << 6);  // uniform base
        uu[q] = rowp[lane];                  // saddr + lane*4 voffset
      }
#pragma unroll
      for (int q = 0; q < 16; ++q) {
        float lo = __uint_as_float(uu[q] << 16);
        float hi = __uint_as_float(uu[q] & 0xFFFF0000u);
        if (q & 1) { accB.x += wq[q] * lo; accB.y += wq[q] * hi; }
        else       { accA.x += wq[q] * lo; accA.y += wq[q] * hi; }
      }
    }
  }

  float2 acc = {accA.x + accB.x, accA.y + accB.y};
  const float2 bb = *(const float2*)(bias + lane * 2);
  float2 outv;
  outv.x = fmaxf(dv * acc.x + bb.x, 0.0f);
  outv.y = fmaxf(dv * acc.y + bb.y, 0.0f);
  hrow[lane] = ((unsigned)f2bf(outv.y) << 16) | (unsigned)f2bf(outv.x);

  if (rr != nullptr) {                        // fused pool dots r=h.wrel t=h.wroot
    const float2 wr = *(const float2*)(wrel + lane * 2);
    const float2 wo = *(const float2*)(wroot + lane * 2);
    float pr = outv.x * wr.x + outv.y * wr.y;
    float pt = outv.x * wo.x + outv.y * wo.y;
#pragma unroll
    for (int d = 32; d > 0; d >>= 1) {
      pr += __shfl_down(pr, d);
      pt += __shfl_down(pt, d);
    }
    if (lane == 0) { rr[wid] = pr; tt[wid] = pt; }
  }
}

// ---------------------------------------------------------------------------
// pool score: score[n] = mask[n]*(sum_in r[src] + t[n] + b); 16 lanes/node.
// ---------------------------------------------------------------------------
__global__ __launch_bounds__(256) void score_agg(const float* __restrict__ r,
                                                 const float* __restrict__ t,
                                                 const float* __restrict__ pb,
                                                 const float* __restrict__ mask,
                                                 const int* __restrict__ offs,
                                                 const int* __restrict__ csr,
                                                 float* __restrict__ score) {
  int grp = threadIdx.x >> 4;
  int gl  = threadIdx.x & 15;
  int nid = blockIdx.x * 16 + grp;
  int b = nid >> 13, n = nid & (N - 1);
  bool live = (mask == nullptr) || (mask[nid] > 0.0f);
  float s = 0.0f;
  if (live) {
    int o0 = offs[b * (N + 1) + n], o1 = offs[b * (N + 1) + n + 1];
    const int* cs = csr + (size_t)b * E;
    const float* rb = r + b * N;
    for (int base = o0; base < o1; base += 16)
      if (base + gl < o1) s += rb[cs[base + gl]];   // r==0 for dead srcs
  }
#pragma unroll
  for (int d = 8; d > 0; d >>= 1) s += __shfl_xor(s, d, 16);
  if (gl == 0) score[nid] = live ? (s + t[nid] + pb[0]) : 0.0f;
}

// ---------------------------------------------------------------------------
// top-k via radix select; index-ordered ties. Keys cached in LDS; parallel
// suffix-scan bucket pick. Writes new mask AND fscale = tanh(score)*mask.
// ---------------------------------------------------------------------------
__device__ __forceinline__ unsigned fkey(float s, float m) {
  if (m <= 0.0f) return 0u;
  unsigned u = __float_as_uint(s);
  return (u & 0x80000000u) ? ~u : (u | 0x80000000u);
}

__global__ __launch_bounds__(1024) void topk_kernel(const float* __restrict__ score,
                                                    const float* __restrict__ mkin,
                                                    float* __restrict__ mkout,
                                                    float* __restrict__ fscale,
                                                    int k) {
  int b = blockIdx.x, tid = threadIdx.x;
  const float* sc = score + b * N;
  float* mk = mkout + b * N;
  float* fs = fscale + b * N;
  __shared__ unsigned keyb[N];        // 32 KB
  __shared__ int hist[256];
  __shared__ int sbuf[1024];
  __shared__ unsigned sh_prefix;
  __shared__ int sh_kneed;

  for (int i = tid; i < N; i += 1024) {
    float m = (mkin == nullptr) ? 1.0f : mkin[b * N + i];
    keyb[i] = fkey(sc[i], m);
  }
  __syncthreads();

  unsigned prefix = 0, hm = 0;
  int kneed = k;
  for (int shift = 24; shift >= 0; shift -= 8) {
    if (tid < 256) hist[tid] = 0;
    __syncthreads();
    for (int i = tid; i < N; i += 1024) {
      unsigned key = keyb[i];
      if ((key & hm) == prefix) atomicAdd(&hist[(key >> shift) & 255], 1);
    }
    __syncthreads();
    if (tid < 256) sbuf[tid] = hist[tid];
    __syncthreads();
    for (int off = 1; off < 256; off <<= 1) {
      int v = (tid < 256 && tid + off < 256) ? sbuf[tid + off] : 0;
      __syncthreads();
      if (tid < 256) sbuf[tid] += v;
      __syncthreads();
    }
    if (tid < 256) {
      int ge = sbuf[tid];
      int gt = (tid < 255) ? sbuf[tid + 1] : 0;
      if (ge >= kneed && gt < kneed) {
        sh_prefix = prefix | ((unsigned)tid << shift);
        sh_kneed = kneed - gt;
      }
    }
    __syncthreads();
    prefix = sh_prefix;
    kneed = sh_kneed;
    hm |= (0xFFu << shift);
    __syncthreads();
  }

  unsigned T = prefix;              // key of the k-th largest
  int base = tid * 8;
  unsigned keys[8];
  int eqf[8];
  int cnt = 0;
#pragma unroll
  for (int q = 0; q < 8; ++q) {
    keys[q] = keyb[base + q];
    eqf[q] = (keys[q] == T) ? 1 : 0;
    cnt += eqf[q];
  }
  sbuf[tid] = cnt; __syncthreads();
  for (int off = 1; off < 1024; off <<= 1) {
    int x = (tid >= off) ? sbuf[tid - off] : 0;
    __syncthreads();
    sbuf[tid] += x;
    __syncthreads();
  }
  int ex = sbuf[tid] - cnt;         // rank base among ties (index order)
#pragma unroll
  for (int q = 0; q < 8; ++q) {
    bool sel = (keys[q] > T) || (eqf[q] && (ex < kneed));
    ex += eqf[q];
    mk[base + q] = sel ? 1.0f : 0.0f;
    fs[base + q] = sel ? tanhf(sc[base + q]) : 0.0f;
  }
}

// ---------------------------------------------------------------------------
// readout partials (bf16 h) + head MLP + log_softmax
// ---------------------------------------------------------------------------
__global__ __launch_bounds__(256) void readout(const unsigned short* __restrict__ h,
                                               float* __restrict__ part) {
  int b = blockIdx.x, c = blockIdx.y;
  int tid = threadIdx.x;
  int f = tid & 127, half = tid >> 7;
  float acc = 0.0f;
  for (int n = c * 256 + half; n < (c + 1) * 256; n += 2)
    acc += bf2f(h[((size_t)b * N + n) * 128 + f]);
  __shared__ float red[256];
  red[tid] = acc; __syncthreads();
  if (half == 0) part[((size_t)b * 32 + c) * 128 + f] = red[f] + red[f + 128];
}

__global__ __launch_bounds__(128) void head(const float* __restrict__ part,
                                            const float* __restrict__ l1w,
                                            const float* __restrict__ l1b,
                                            const float* __restrict__ l2w,
                                            const float* __restrict__ l2b,
                                            float* __restrict__ out) {
  int b = blockIdx.x, f = threadIdx.x;
  float g = 0.0f;
  for (int c = 0; c < 32; ++c) g += part[((size_t)b * 32 + c) * 128 + f];
  g *= (1.0f / (float)K2);
  __shared__ float gs[128], hh[128], lg[10];
  gs[f] = g; __syncthreads();
  float a = l1b[f];
  for (int kk = 0; kk < 128; ++kk) a += gs[kk] * l1w[kk * 128 + f];
  hh[f] = fmaxf(a, 0.0f); __syncthreads();
  if (f < 10) {
    float l = l2b[f];
    for (int j = 0; j < 128; ++j) l += hh[j] * l2w[j * 10 + f];
    lg[f] = l;
  }
  __syncthreads();
  if (f == 0) {
    float m = lg[0];
    for (int c = 1; c < 10; ++c) m = fmaxf(m, lg[c]);
    float s = 0.0f;
    for (int c = 0; c < 10; ++c) s += expf(lg[c] - m);
    float lse = m + logf(s);
    for (int c = 0; c < 10; ++c) out[b * 10 + c] = lg[c] - lse;
  }
}

// ---------------------------------------------------------------------------
extern "C" void kernel_launch(void* const* d_in, const int* in_sizes, int n_in,
                              void* d_out, int out_size, void* d_ws, size_t ws_size,
                              hipStream_t stream) {
  (void)in_sizes; (void)n_in; (void)out_size; (void)ws_size;
  const float* x       = (const float*)d_in[0];
  const int*   ei      = (const int*)d_in[1];
  const float* W1      = (const float*)d_in[2];
  const float* b1      = (const float*)d_in[3];
  const float* p1_wrel = (const float*)d_in[4];
  const float* p1_wroot= (const float*)d_in[5];
  const float* p1_b    = (const float*)d_in[6];
  const float* W2      = (const float*)d_in[7];
  const float* b2      = (const float*)d_in[8];
  const float* p2_wrel = (const float*)d_in[9];
  const float* p2_wroot= (const float*)d_in[10];
  const float* p2_b    = (const float*)d_in[11];
  const float* W3      = (const float*)d_in[12];
  const float* b3      = (const float*)d_in[13];
  const float* l1w     = (const float*)d_in[14];
  const float* l1b     = (const float*)d_in[15];
  const float* l2w     = (const float*)d_in[16];
  const float* l2b     = (const float*)d_in[17];
  float* out = (float*)d_out;

  // workspace carve-up
  char* p = (char*)d_ws;
  auto alloc = [&](size_t bytes) {
    char* r = p;
    p += ((bytes + 255) & ~(size_t)255);
    return r;
  };
  unsigned short* h   = (unsigned short*)alloc((size_t)B * N * H * 2);   // bf16
  unsigned short* tmp = (unsigned short*)alloc((size_t)B * N * H * 2);   // bf16
  int*      offs   = (int*)alloc((size_t)B * (N + 1) * 4);
  int*      csr    = (int*)alloc((size_t)B * E * 4);
  unsigned* pbuf   = (unsigned*)alloc((size_t)B * E * 4);
  int*      bchist = (int*)alloc((size_t)B * CHUNKS * NBK * 4);
  int*      cursor = (int*)alloc((size_t)B * CHUNKS * NBK * 4);
  int*      bbase  = (int*)alloc((size_t)B * (NBK + 1) * 4);
  float* dinv   = (float*)alloc((size_t)B * N * 4);
  float* mask   = (float*)alloc((size_t)B * N * 4);
  float* rr     = (float*)alloc((size_t)B * N * 4);
  float* tt     = (float*)alloc((size_t)B * N * 4);
  float* score  = (float*)alloc((size_t)B * N * 4);
  float* fscale = (float*)alloc((size_t)B * N * 4);
  float* part   = (float*)alloc((size_t)B * 32 * H * 4);
  unsigned short* Wts = (unsigned short*)alloc(3 * 128 * 128 * 2);

  // CSR build (streaming counting sort) + weight prep
  hist_pass<<<B * CHUNKS, 256, 0, stream>>>(ei, bchist);
  bucket_scan<<<B, 256, 0, stream>>>(bchist, cursor, bbase);
  bin_scatter<<<B * CHUNKS, 256, 0, stream>>>(ei, cursor, pbuf);
  final_scatter<<<B * NBK, 256, 0, stream>>>(pbuf, bbase, csr, offs, dinv);
  prep_wt3<<<3, 256, 0, stream>>>(W1, W2, W3, Wts);

  // ---- layer 1 + pool 1 (all nodes live; dinv from final_scatter)
  gemm_mfma<false><<<(B * N) / 128, 256, 0, stream>>>(x, Wts, tmp, nullptr);
  gcn_agg3<true><<<B * N / 4, 256, 0, stream>>>((const unsigned*)tmp, dinv, offs, csr, b1,
                                                (unsigned*)h, p1_wrel, p1_wroot, rr, tt);
  score_agg<<<B * N / 16, 256, 0, stream>>>(rr, tt, p1_b, nullptr, offs, csr, score);
  topk_kernel<<<B, 1024, 0, stream>>>(score, nullptr, mask, fscale, K1);

  // ---- layer 2 + pool 2 (pool-1 scaling fused into GEMM A-frag load)
  gemm_mfma<true><<<(B * N) / 128, 256, 0, stream>>>(h, Wts + 128 * 128, tmp, fscale);
  deg_masked<<<B * N / 16, 256, 0, stream>>>(mask, offs, csr, dinv);
  gcn_agg3<false><<<B * N / 4, 256, 0, stream>>>((const unsigned*)tmp, dinv, offs, csr, b2,
                                                 (unsigned*)h, p2_wrel, p2_wroot, rr, tt);
  score_agg<<<B * N / 16, 256, 0, stream>>>(rr, tt, p2_b, mask, offs, csr, score);
  topk_kernel<<<B, 1024, 0, stream>>>(score, mask, mask, fscale, K2);

  // ---- layer 3
  gemm_mfma<true><<<(B * N) / 128, 256, 0, stream>>>(h, Wts + 2 * 128 * 128, tmp, fscale);
  deg_masked<<<B * N / 16, 256, 0, stream>>>(mask, offs, csr, dinv);
  gcn_agg3<false><<<B * N / 4, 256, 0, stream>>>((const unsigned*)tmp, dinv, offs, csr, b3,
                                                 (unsigned*)h, nullptr, nullptr, nullptr, nullptr);

  // ---- readout + head
  readout<<<dim3(B, 32), 256, 0, stream>>>(h, part);
  head<<<B, 128, 0, stream>>>(part, l1w, l1b, l2w, l2b, out);
}